// Round 9
// baseline (145.900 us; speedup 1.0000x reference)
//
#include <hip/hip_runtime.h>
#include <hip/hip_fp16.h>
#include <math.h>

// FrFT (Ozaktas, 0.5<a<1.5): x[256,4096] f32, order f32 -> Re(complex64) f32
// out[b*4096+j]. R22: hoist the chirp-weight trig out of s2.
//   R8 diagnosis: s2 is VALU-bound (61% busy = 28us) and 86% of that VALU is
//   __cosf weight-gen, computed 4x redundantly across b-tile blocks.
//   Fix: wgen precomputes W = cos(ph) once (33.5M distinct weights) into two
//   f16 planes in ws, stored in MFMA-fragment order [jf][ks][lane][8] ->
//   s2g's B-operand is one coalesced dwordx4 per lane. Identical expression
//   tree (quadratic phase, __cosf, pkrtz) -> bit-identical numerics.
//   Needs ws >= 69.2 MB; tiered launcher falls back to the proven R21 path
//   (byte-identical) if ws is small, then R13 paths.
//   s2g XCD swizzle: 4 b-variants of each j-tile on one XCD (W L2-resident).

#define NN 4096
#define BB 256
#define KK (2*NN - 1)
#define CHW 512

typedef unsigned int uint;
typedef __attribute__((ext_vector_type(4))) float f32x4;
typedef __attribute__((ext_vector_type(4))) uint u32x4;
typedef __attribute__((ext_vector_type(8))) _Float16 half8;
typedef __attribute__((ext_vector_type(4))) _Float16 half4;
typedef __attribute__((ext_vector_type(2))) __fp16 fp16x2;

struct LitConsts { float c, q, scale, pe; };

__device__ __forceinline__ LitConsts get_lit(const float* order) {
  float a = order[0];
  float alpha = a * (float)M_PI * 0.5f;
  float sina = sinf(alpha);
  float tana2 = tanf(alpha * 0.5f);
  LitConsts L;
  L.c = (float)M_PI / (float)NN / sina / 4.0f;
  L.q = ((float)M_PI / (float)NN) * (tana2 * 0.25f);
  L.scale = sqrtf(L.c / (float)M_PI);
  L.pe = -(1.0f - a) * (float)M_PI * 0.25f;
  return L;
}

__device__ __forceinline__ float xload(const float* __restrict__ x, uint idx, uint cap) {
  return (idx < cap) ? x[idx] : 0.f;
}

__device__ __forceinline__ uint pk2(float a, float b) {
  fp16x2 h = __builtin_amdgcn_cvt_pkrtz(a, b);
  return __builtin_bit_cast(uint, h);
}

__device__ __forceinline__ half8 pack8(const float* wv) {
  u32x4 u = { pk2(wv[0], wv[1]), pk2(wv[2], wv[3]),
              pk2(wv[4], wv[5]), pk2(wv[6], wv[7]) };
  return __builtin_bit_cast(half8, u);
}

// granule position permutation (16B granules within a 64-granule row)
__device__ __forceinline__ int gpos(int s) { return s ^ (s >> 3); }

// ---- W precompute: plane[parity] [jf 0..255][ks 0..127][lane 0..63][8] f16 ----
__global__ __launch_bounds__(256) void wgen(const float* __restrict__ order,
                                            _Float16* __restrict__ We,
                                            _Float16* __restrict__ Wo) {
  const int id = blockIdx.x;          // 0..511
  const int parity = id >> 8;         // 0: even r=2i, 1: odd r=2i+1
  const int jf = id & 255;
  const int tid = threadIdx.x;
  const LitConsts L = get_lit(order);
  const float P2 = 4.f * (L.c - L.q);
  _Float16* Wp = parity ? Wo : We;

#pragma unroll 4
  for (int m = 0; m < 32; ++m) {
    const int s = m * 256 + tid;      // slot within (parity, jf): ks*64 + lane
    const int ks = s >> 6, l = s & 63;
    const int j = jf * 16 + (l & 15);
    const int i0 = ks * 32 + (l >> 4) * 8;
    const int n = 2 * j - (NN - 1);
    const float jbase = fmaf(-L.q, (float)(n * n), L.pe);
    const int r0 = 2 * i0 + parity;
    const int k0 = r0 - (NN - 1);
    const float bk  = -L.q * (float)(k0 * k0);
    const float qk0 =  L.q * (float)k0;
    const int d0 = 2 * j - r0;
    const float P0 = fmaf(L.c, (float)(d0 * d0), jbase + bk);
    const float P1 = -4.f * fmaf(L.c, (float)d0, qk0);
    float wv[8];
#pragma unroll
    for (int e = 0; e < 8; ++e) {
      const float ef = (float)e;
      float t = __cosf(fmaf(ef, fmaf(ef, P2, P1), P0));
      if (parity && (i0 + e) > (NN - 2)) t = 0.f;  // r=8191 pad does not exist
      wv[e] = t;
    }
    *(u32x4*)(Wp + (size_t)jf * 65536 + (size_t)s * 8) =
        __builtin_bit_cast(u32x4, pack8(wv));
  }
}

// ---- stage 1: sinc interp GEMM; 256 blocks x 1024 thr; tile 64b x 64s ----
__global__ __launch_bounds__(1024, 4) void s1_v4(const float* __restrict__ x,
                                                 _Float16* __restrict__ xiT) {
  __shared__ __align__(16) _Float16 U[2][64][CHW];   // 128 KB
  float* redf = (float*)&U[0][0][0];                 // aliased after k-loop
  const int tid = threadIdx.x;
  const int w = tid >> 6, lane = tid & 63;
  const int l15 = lane & 15, lhi = lane >> 4;
  const int kq = w & 7, fh = w >> 3;
  const int id = blockIdx.x, xcd = id & 7;
  const int b0 = (xcd >> 1) * 64;
  const int s0 = ((xcd & 1) | ((id >> 3) << 1)) * 64;
  const int srow = tid >> 4, t15 = tid & 15;
  const int swz = (srow & 7) << 4;
  const float C2PI = 0.63661977236758134f;

  const float* xrow = x + (size_t)(b0 + srow) * NN;

  f32x4 acc[4][2] = {};
  f32x4 pf[4][2];

  { // prologue: stage chunk 0
#pragma unroll
    for (int k = 0; k < 4; ++k) {
      const f32x4* p = (const f32x4*)(xrow + (t15 + 16 * k) * 8);
      f32x4 a = p[0], b = p[1];
      u32x4 d = { pk2(a[0], a[1]), pk2(a[2], a[3]), pk2(b[0], b[1]), pk2(b[2], b[3]) };
      const int s = t15 + 16 * k;
      *(u32x4*)((char*)&U[0][srow][0] + ((gpos(s) << 4) ^ swz)) = d;
    }
  }

  for (int ch = 0; ch < 8; ++ch) {
    __syncthreads();
    const int cb = ch & 1;
    if (ch < 7) {
#pragma unroll
      for (int k = 0; k < 4; ++k) {
        const f32x4* p = (const f32x4*)(xrow + (ch + 1) * CHW + (t15 + 16 * k) * 8);
        pf[k][0] = p[0]; pf[k][1] = p[1];
      }
    }
#pragma unroll
    for (int st = 0; st < 2; ++st) {
      const int sg = kq * 8 + st * 4 + lhi;
      const int go = gpos(sg) << 4;
      half8 af[4];
#pragma unroll
      for (int fm = 0; fm < 4; ++fm) {
        const int row = fm * 16 + l15;
        af[fm] = *(const half8*)((const char*)&U[cb][row][0] + (go ^ ((row & 7) << 4)));
      }
      const int i0 = ch * CHW + kq * 64 + st * 32 + lhi * 8;
#pragma unroll
      for (int g = 0; g < 2; ++g) {
        const int t0 = (s0 + (fh * 2 + g) * 16 + l15) - i0;
        float wv[8];
#pragma unroll
        for (int e = 0; e < 8; ++e) {
          const int t = t0 - e;
          const float sgn = (t & 1) ? -C2PI : C2PI;
          wv[e] = __fdividef(sgn, (float)(2 * t + 1));
        }
        const half8 bh = pack8(wv);
#pragma unroll
        for (int fm = 0; fm < 4; ++fm)
          acc[fm][g] = __builtin_amdgcn_mfma_f32_16x16x32_f16(af[fm], bh, acc[fm][g], 0, 0, 0);
      }
    }
    if (ch < 7) {
      char* base = (char*)&U[cb ^ 1][srow][0];
#pragma unroll
      for (int k = 0; k < 4; ++k) {
        u32x4 d = { pk2(pf[k][0][0], pf[k][0][1]), pk2(pf[k][0][2], pf[k][0][3]),
                    pk2(pf[k][1][0], pf[k][1][1]), pk2(pf[k][1][2], pf[k][1][3]) };
        const int s = t15 + 16 * k;
        *(u32x4*)(base + ((gpos(s) << 4) ^ swz)) = d;
      }
    }
  }

  // 8 kq-partials -> 2 red planes (aliased over U) in 4 barrier rounds
#pragma unroll
  for (int rnd = 0; rnd < 4; ++rnd) {
    __syncthreads();
    if ((kq >> 1) == rnd) {
      const int pl = kq & 1;
#pragma unroll
      for (int fm = 0; fm < 4; ++fm)
#pragma unroll
        for (int g = 0; g < 2; ++g)
#pragma unroll
          for (int rr = 0; rr < 4; ++rr) {
            float* p = &redf[((pl * 64) + fm * 16 + lhi * 4 + rr) * 68 + (fh * 2 + g) * 16 + l15];
            if (rnd == 0) *p = acc[fm][g][rr];
            else          *p += acc[fm][g][rr];
          }
    }
  }
  __syncthreads();

  const int c0 = t15 * 4;
  half4 h;
#pragma unroll
  for (int e = 0; e < 4; ++e)
    h[e] = (_Float16)(redf[(srow) * 68 + c0 + e] + redf[(64 + srow) * 68 + c0 + e]);
  *(half4*)(xiT + (size_t)(b0 + srow) * NN + s0 + c0) = h;
}

// ---- stage 2 (R22): pure GEMM with precomputed W; 256 blocks x 1024 thr ----
__global__ __launch_bounds__(1024, 4) void s2g(const float* __restrict__ x,
                                               const _Float16* __restrict__ xiT,
                                               const _Float16* __restrict__ We,
                                               const _Float16* __restrict__ Wo,
                                               const float* __restrict__ order,
                                               float* __restrict__ out) {
  __shared__ __align__(16) _Float16 U[2][64][CHW];
  float* redf = (float*)&U[0][0][0];
  const int tid = threadIdx.x;
  const int w = tid >> 6, lane = tid & 63;
  const int l15 = lane & 15, lhi = lane >> 4;
  const int kq = w & 7, fh = w >> 3;
  const int id = blockIdx.x;
  const int xcd = id & 7, rest = id >> 3;
  const int bt = rest & 3, jlo = rest >> 2;
  const int jt = xcd * 8 + jlo;                 // same-jt blocks -> same XCD
  const int b0 = bt * 64, j0 = jt * 64;
  const int srow = tid >> 4, t15 = tid & 15;
  const int swz = (srow & 7) << 4;

  const LitConsts L = get_lit(order);

  const float* xrow = x + (size_t)(b0 + srow) * NN;
  const _Float16* orow = xiT + (size_t)(b0 + srow) * NN;
  // W fragment base for this wave: frag(ch,st,g) at + ch*8192 + st*512 + g*65536
  const size_t wboff = (size_t)(jt * 4 + fh * 2) * 65536 + (size_t)kq * 1024 + (size_t)lane * 8;
  const _Float16* weB = We + wboff;
  const _Float16* woB = Wo + wboff;

  f32x4 acc[4][2] = {};
  f32x4 pf[4][2];
  u32x4 po[4];

  { // prologue: stage even chunk 0
#pragma unroll
    for (int k = 0; k < 4; ++k) {
      const f32x4* p = (const f32x4*)(xrow + (t15 + 16 * k) * 8);
      f32x4 a = p[0], b = p[1];
      u32x4 d = { pk2(a[0], a[1]), pk2(a[2], a[3]), pk2(b[0], b[1]), pk2(b[2], b[3]) };
      const int s = t15 + 16 * k;
      *(u32x4*)((char*)&U[0][srow][0] + ((gpos(s) << 4) ^ swz)) = d;
    }
  }

  // EVEN pass (r = 2i, A from x); ch=7 prefetches odd chunk 0 from xiT
  for (int ch = 0; ch < 8; ++ch) {
    __syncthreads();
    const int cb = ch & 1;
    u32x4 wf[2][2];
#pragma unroll
    for (int st = 0; st < 2; ++st)
#pragma unroll
      for (int g = 0; g < 2; ++g)
        wf[st][g] = *(const u32x4*)(weB + (size_t)ch * 8192 + st * 512 + g * 65536);
    if (ch < 7) {
#pragma unroll
      for (int k = 0; k < 4; ++k) {
        const f32x4* p = (const f32x4*)(xrow + (ch + 1) * CHW + (t15 + 16 * k) * 8);
        pf[k][0] = p[0]; pf[k][1] = p[1];
      }
    } else {
#pragma unroll
      for (int k = 0; k < 4; ++k)
        po[k] = *(const u32x4*)(orow + (t15 + 16 * k) * 8);
    }
#pragma unroll
    for (int st = 0; st < 2; ++st) {
      const int sg = kq * 8 + st * 4 + lhi;
      const int go = gpos(sg) << 4;
      half8 af[4];
#pragma unroll
      for (int fm = 0; fm < 4; ++fm) {
        const int row = fm * 16 + l15;
        af[fm] = *(const half8*)((const char*)&U[cb][row][0] + (go ^ ((row & 7) << 4)));
      }
#pragma unroll
      for (int g = 0; g < 2; ++g) {
        const half8 bh = __builtin_bit_cast(half8, wf[st][g]);
#pragma unroll
        for (int fm = 0; fm < 4; ++fm)
          acc[fm][g] = __builtin_amdgcn_mfma_f32_16x16x32_f16(af[fm], bh, acc[fm][g], 0, 0, 0);
      }
    }
    char* base = (char*)&U[cb ^ 1][srow][0];
    if (ch < 7) {
#pragma unroll
      for (int k = 0; k < 4; ++k) {
        u32x4 d = { pk2(pf[k][0][0], pf[k][0][1]), pk2(pf[k][0][2], pf[k][0][3]),
                    pk2(pf[k][1][0], pf[k][1][1]), pk2(pf[k][1][2], pf[k][1][3]) };
        const int s = t15 + 16 * k;
        *(u32x4*)(base + ((gpos(s) << 4) ^ swz)) = d;
      }
    } else {
#pragma unroll
      for (int k = 0; k < 4; ++k) {
        const int s = t15 + 16 * k;
        *(u32x4*)(base + ((gpos(s) << 4) ^ swz)) = po[k];
      }
    }
  }

  // ODD pass (r = 2i+1, A from xiT); odd chunk 0 already in U[0]
  for (int ch = 0; ch < 8; ++ch) {
    __syncthreads();
    const int cb = ch & 1;
    u32x4 wf[2][2];
#pragma unroll
    for (int st = 0; st < 2; ++st)
#pragma unroll
      for (int g = 0; g < 2; ++g)
        wf[st][g] = *(const u32x4*)(woB + (size_t)ch * 8192 + st * 512 + g * 65536);
    if (ch < 7) {
#pragma unroll
      for (int k = 0; k < 4; ++k)
        po[k] = *(const u32x4*)(orow + (ch + 1) * CHW + (t15 + 16 * k) * 8);
    }
#pragma unroll
    for (int st = 0; st < 2; ++st) {
      const int sg = kq * 8 + st * 4 + lhi;
      const int go = gpos(sg) << 4;
      half8 af[4];
#pragma unroll
      for (int fm = 0; fm < 4; ++fm) {
        const int row = fm * 16 + l15;
        af[fm] = *(const half8*)((const char*)&U[cb][row][0] + (go ^ ((row & 7) << 4)));
      }
#pragma unroll
      for (int g = 0; g < 2; ++g) {
        const half8 bh = __builtin_bit_cast(half8, wf[st][g]);
#pragma unroll
        for (int fm = 0; fm < 4; ++fm)
          acc[fm][g] = __builtin_amdgcn_mfma_f32_16x16x32_f16(af[fm], bh, acc[fm][g], 0, 0, 0);
      }
    }
    if (ch < 7) {
      char* base = (char*)&U[cb ^ 1][srow][0];
#pragma unroll
      for (int k = 0; k < 4; ++k) {
        const int s = t15 + 16 * k;
        *(u32x4*)(base + ((gpos(s) << 4) ^ swz)) = po[k];
      }
    }
  }

  // reduce (red aliased over U[0]) + scaled store
#pragma unroll
  for (int rnd = 0; rnd < 4; ++rnd) {
    __syncthreads();
    if ((kq >> 1) == rnd) {
      const int pl = kq & 1;
#pragma unroll
      for (int fm = 0; fm < 4; ++fm)
#pragma unroll
        for (int g = 0; g < 2; ++g)
#pragma unroll
          for (int rr = 0; rr < 4; ++rr) {
            float* p = &redf[((pl * 64) + fm * 16 + lhi * 4 + rr) * 68 + (fh * 2 + g) * 16 + l15];
            if (rnd == 0) *p = acc[fm][g][rr];
            else          *p += acc[fm][g][rr];
          }
    }
  }
  __syncthreads();

  const int c0 = t15 * 4;
  f32x4 v;
#pragma unroll
  for (int e = 0; e < 4; ++e)
    v[e] = L.scale * (redf[(srow) * 68 + c0 + e] + redf[(64 + srow) * 68 + c0 + e]);
  *(f32x4*)(out + (size_t)(b0 + srow) * NN + j0 + c0) = v;
}

// ---- stage 2 (R21 fallback): in-loop weights ----
__global__ __launch_bounds__(1024, 4) void s2_v4(const float* __restrict__ x,
                                                 const _Float16* __restrict__ xiT,
                                                 const float* __restrict__ order,
                                                 float* __restrict__ out) {
  __shared__ __align__(16) _Float16 U[2][64][CHW];
  float* redf = (float*)&U[0][0][0];
  const int tid = threadIdx.x;
  const int w = tid >> 6, lane = tid & 63;
  const int l15 = lane & 15, lhi = lane >> 4;
  const int kq = w & 7, fh = w >> 3;
  const int id = blockIdx.x, xcd = id & 7;
  const int b0 = (xcd >> 1) * 64;
  const int j0 = ((xcd & 1) | ((id >> 3) << 1)) * 64;
  const int srow = tid >> 4, t15 = tid & 15;
  const int swz = (srow & 7) << 4;

  const LitConsts L = get_lit(order);
  const float P2 = 4.f * (L.c - L.q);
  int jl[2]; float jbase[2];
#pragma unroll
  for (int g = 0; g < 2; ++g) {
    jl[g] = j0 + (fh * 2 + g) * 16 + l15;
    const int n = 2 * jl[g] - (NN - 1);
    jbase[g] = fmaf(-L.q, (float)(n * n), L.pe);
  }

  const float* xrow = x + (size_t)(b0 + srow) * NN;
  const _Float16* orow = xiT + (size_t)(b0 + srow) * NN;

  f32x4 acc[4][2] = {};
  f32x4 pf[4][2];
  u32x4 po[4];

  {
#pragma unroll
    for (int k = 0; k < 4; ++k) {
      const f32x4* p = (const f32x4*)(xrow + (t15 + 16 * k) * 8);
      f32x4 a = p[0], b = p[1];
      u32x4 d = { pk2(a[0], a[1]), pk2(a[2], a[3]), pk2(b[0], b[1]), pk2(b[2], b[3]) };
      const int s = t15 + 16 * k;
      *(u32x4*)((char*)&U[0][srow][0] + ((gpos(s) << 4) ^ swz)) = d;
    }
  }

  for (int ch = 0; ch < 8; ++ch) {
    __syncthreads();
    const int cb = ch & 1;
    if (ch < 7) {
#pragma unroll
      for (int k = 0; k < 4; ++k) {
        const f32x4* p = (const f32x4*)(xrow + (ch + 1) * CHW + (t15 + 16 * k) * 8);
        pf[k][0] = p[0]; pf[k][1] = p[1];
      }
    } else {
#pragma unroll
      for (int k = 0; k < 4; ++k)
        po[k] = *(const u32x4*)(orow + (t15 + 16 * k) * 8);
    }
#pragma unroll
    for (int st = 0; st < 2; ++st) {
      const int sg = kq * 8 + st * 4 + lhi;
      const int go = gpos(sg) << 4;
      half8 af[4];
#pragma unroll
      for (int fm = 0; fm < 4; ++fm) {
        const int row = fm * 16 + l15;
        af[fm] = *(const half8*)((const char*)&U[cb][row][0] + (go ^ ((row & 7) << 4)));
      }
      const int i0 = ch * CHW + kq * 64 + st * 32 + lhi * 8;
      const int r0 = 2 * i0;
      const int k0 = r0 - (NN - 1);
      const float bk  = -L.q * (float)(k0 * k0);
      const float qk0 =  L.q * (float)k0;
#pragma unroll
      for (int g = 0; g < 2; ++g) {
        const int d0 = 2 * jl[g] - r0;
        const float P0 = fmaf(L.c, (float)(d0 * d0), jbase[g] + bk);
        const float P1 = -4.f * fmaf(L.c, (float)d0, qk0);
        float wv[8];
#pragma unroll
        for (int e = 0; e < 8; ++e) {
          const float ef = (float)e;
          wv[e] = __cosf(fmaf(ef, fmaf(ef, P2, P1), P0));
        }
        const half8 bh = pack8(wv);
#pragma unroll
        for (int fm = 0; fm < 4; ++fm)
          acc[fm][g] = __builtin_amdgcn_mfma_f32_16x16x32_f16(af[fm], bh, acc[fm][g], 0, 0, 0);
      }
    }
    char* base = (char*)&U[cb ^ 1][srow][0];
    if (ch < 7) {
#pragma unroll
      for (int k = 0; k < 4; ++k) {
        u32x4 d = { pk2(pf[k][0][0], pf[k][0][1]), pk2(pf[k][0][2], pf[k][0][3]),
                    pk2(pf[k][1][0], pf[k][1][1]), pk2(pf[k][1][2], pf[k][1][3]) };
        const int s = t15 + 16 * k;
        *(u32x4*)(base + ((gpos(s) << 4) ^ swz)) = d;
      }
    } else {
#pragma unroll
      for (int k = 0; k < 4; ++k) {
        const int s = t15 + 16 * k;
        *(u32x4*)(base + ((gpos(s) << 4) ^ swz)) = po[k];
      }
    }
  }

  for (int ch = 0; ch < 8; ++ch) {
    __syncthreads();
    const int cb = ch & 1;
    if (ch < 7) {
#pragma unroll
      for (int k = 0; k < 4; ++k)
        po[k] = *(const u32x4*)(orow + (ch + 1) * CHW + (t15 + 16 * k) * 8);
    }
#pragma unroll
    for (int st = 0; st < 2; ++st) {
      const int sg = kq * 8 + st * 4 + lhi;
      const int go = gpos(sg) << 4;
      half8 af[4];
#pragma unroll
      for (int fm = 0; fm < 4; ++fm) {
        const int row = fm * 16 + l15;
        af[fm] = *(const half8*)((const char*)&U[cb][row][0] + (go ^ ((row & 7) << 4)));
      }
      const int i0 = ch * CHW + kq * 64 + st * 32 + lhi * 8;
      const int r0 = 2 * i0 + 1;
      const int k0 = r0 - (NN - 1);
      const float bk  = -L.q * (float)(k0 * k0);
      const float qk0 =  L.q * (float)k0;
#pragma unroll
      for (int g = 0; g < 2; ++g) {
        const int d0 = 2 * jl[g] - r0;
        const float P0 = fmaf(L.c, (float)(d0 * d0), jbase[g] + bk);
        const float P1 = -4.f * fmaf(L.c, (float)d0, qk0);
        float wv[8];
#pragma unroll
        for (int e = 0; e < 8; ++e) {
          const float ef = (float)e;
          float t = __cosf(fmaf(ef, fmaf(ef, P2, P1), P0));
          if (i0 + e > NN - 2) t = 0.f;
          wv[e] = t;
        }
        const half8 bh = pack8(wv);
#pragma unroll
        for (int fm = 0; fm < 4; ++fm)
          acc[fm][g] = __builtin_amdgcn_mfma_f32_16x16x32_f16(af[fm], bh, acc[fm][g], 0, 0, 0);
      }
    }
    if (ch < 7) {
      char* base = (char*)&U[cb ^ 1][srow][0];
#pragma unroll
      for (int k = 0; k < 4; ++k) {
        const int s = t15 + 16 * k;
        *(u32x4*)(base + ((gpos(s) << 4) ^ swz)) = po[k];
      }
    }
  }

#pragma unroll
  for (int rnd = 0; rnd < 4; ++rnd) {
    __syncthreads();
    if ((kq >> 1) == rnd) {
      const int pl = kq & 1;
#pragma unroll
      for (int fm = 0; fm < 4; ++fm)
#pragma unroll
        for (int g = 0; g < 2; ++g)
#pragma unroll
          for (int rr = 0; rr < 4; ++rr) {
            float* p = &redf[((pl * 64) + fm * 16 + lhi * 4 + rr) * 68 + (fh * 2 + g) * 16 + l15];
            if (rnd == 0) *p = acc[fm][g][rr];
            else          *p += acc[fm][g][rr];
          }
    }
  }
  __syncthreads();

  const int c0 = t15 * 4;
  f32x4 v;
#pragma unroll
  for (int e = 0; e < 4; ++e)
    v[e] = L.scale * (redf[(srow) * 68 + c0 + e] + redf[(64 + srow) * 68 + c0 + e]);
  *(f32x4*)(out + (size_t)(b0 + srow) * NN + j0 + c0) = v;
}

// ======================= R13 proven fallback (small ws) =======================

__global__ __launch_bounds__(256) void frft_interp(const float* __restrict__ x,
                                                   __half* __restrict__ xi,
                                                   int b_lo, int cnt,
                                                   uint xi_cap, uint x_cap) {
  __shared__ __align__(16) float wt1[32][64];
  __shared__ __align__(16) float xt[32][64];
  const int tid = threadIdx.x;
  const int s0 = blockIdx.x * 64, cb0 = blockIdx.y * 64;
  const int tx = tid & 15, ty = tid >> 4;
  const int ss0 = ty * 4, bb0 = tx * 4;

  float acc[4][4] = {};
  for (int i0 = 0; i0 < NN; i0 += 32) {
#pragma unroll
    for (int e = 0; e < 8; ++e) {
      int idx = tid + e * 256, qq = idx >> 6, ss = idx & 63;
      int t = s0 + ss - (i0 + qq);
      float sgn = (t & 1) ? -0.63661977236758134f : 0.63661977236758134f;
      wt1[qq][ss] = __fdividef(sgn, (float)(2 * t + 1));
    }
#pragma unroll
    for (int e = 0; e < 8; ++e) {
      int idx = tid + e * 256, qq = idx >> 6, bb = idx & 63;
      xt[qq][bb] = xload(x, (uint)(b_lo + cb0 + bb) * NN + (i0 + qq), x_cap);
    }
    __syncthreads();
#pragma unroll
    for (int qq = 0; qq < 32; ++qq) {
      float4 wv = *(const float4*)&wt1[qq][ss0];
      float4 uv = *(const float4*)&xt[qq][bb0];
      float w[4] = {wv.x, wv.y, wv.z, wv.w};
      float u[4] = {uv.x, uv.y, uv.z, uv.w};
#pragma unroll
      for (int aa = 0; aa < 4; ++aa)
#pragma unroll
        for (int cc = 0; cc < 4; ++cc) acc[aa][cc] = fmaf(w[aa], u[cc], acc[aa][cc]);
    }
    __syncthreads();
  }
#pragma unroll
  for (int aa = 0; aa < 4; ++aa) {
    int s = s0 + ss0 + aa;
    if (s < NN - 1) {
#pragma unroll
      for (int cc = 0; cc < 4; ++cc) {
        int cb = cb0 + bb0 + cc;
        if (cb < cnt) {
          uint o = (uint)s * (uint)cnt + (uint)cb;
          if (o < xi_cap) xi[o] = __float2half(acc[aa][cc]);
        }
      }
    }
  }
}

#define TJ 32
#define TB 64
#define TK 32
__global__ __launch_bounds__(256) void frft_gemm(const float* __restrict__ x,
                                                 const __half* __restrict__ xi,
                                                 const float* __restrict__ order,
                                                 float* __restrict__ out,
                                                 int b_lo, int cnt,
                                                 uint xi_cap, uint x_cap,
                                                 uint out_capf) {
  __shared__ __align__(16) float wt[TK][TJ];
  __shared__ __align__(16) float ut[TK][TB];
  const int tid = threadIdx.x;
  const int j0 = blockIdx.x * TJ, cb0 = blockIdx.y * TB;
  const int tx = tid & 15, ty = tid >> 4;
  const int jj0 = ty * 2, bb0 = tx * 4;

  LitConsts L = get_lit(order);
  float acc[2][4] = {};

  for (int r0 = 0; r0 < KK; r0 += TK) {
#pragma unroll
    for (int e = 0; e < 4; ++e) {
      int idx = tid + e * 256, qq = idx >> 5, jj = idx & 31;
      int r = r0 + qq;
      float wv = 0.f;
      if (r < KK) {
        int j = j0 + jj;
        int n = 2 * j - (NN - 1);
        int d = 2 * j - r;
        int k = r - (NN - 1);
        float base = fmaf(-L.q, (float)(n * n), L.pe);
        float ph = fmaf(L.c, (float)(d * d), fmaf(-L.q, (float)(k * k), base));
        wv = __cosf(ph);
      }
      wt[qq][jj] = wv;
    }
#pragma unroll
    for (int e = 0; e < 8; ++e) {
      int idx = tid + e * 256, qq = idx >> 6, bb = idx & 63;
      int r = r0 + qq, cb = cb0 + bb;
      float v = 0.f;
      if (r < KK && cb < cnt) {
        if (r & 1) {
          uint o = (uint)(r >> 1) * (uint)cnt + (uint)cb;
          v = (o < xi_cap) ? __half2float(xi[o]) : 0.f;
        } else {
          v = xload(x, (uint)(b_lo + cb) * NN + (uint)(r >> 1), x_cap);
        }
      }
      ut[qq][bb] = v;
    }
    __syncthreads();
#pragma unroll
    for (int qq = 0; qq < TK; ++qq) {
      float2 wv = *(const float2*)&wt[qq][jj0];
      float4 uv = *(const float4*)&ut[qq][bb0];
      float w[2] = {wv.x, wv.y};
      float u[4] = {uv.x, uv.y, uv.z, uv.w};
#pragma unroll
      for (int aa = 0; aa < 2; ++aa)
#pragma unroll
        for (int cc = 0; cc < 4; ++cc)
          acc[aa][cc] = fmaf(w[aa], u[cc], acc[aa][cc]);
    }
    __syncthreads();
  }

#pragma unroll
  for (int aa = 0; aa < 2; ++aa) {
    int j = j0 + jj0 + aa;
#pragma unroll
    for (int cc = 0; cc < 4; ++cc) {
      int cb = cb0 + bb0 + cc;
      if (cb < cnt) {
        uint idx = (uint)(b_lo + cb) * NN + (uint)j;
        if (idx < out_capf) out[idx] = L.scale * acc[aa][cc];
      }
    }
  }
}

__global__ __launch_bounds__(256) void frft_gemm1(const float* __restrict__ x,
                                                  const float* __restrict__ order,
                                                  float* __restrict__ out,
                                                  uint x_cap, uint out_capf) {
  __shared__ float xrow[NN];
  __shared__ float xio[NN - 1];
  __shared__ float red[4][64];
  const int tid = threadIdx.x;
  const int j0 = blockIdx.x * 64;
  LitConsts L = get_lit(order);

#pragma unroll
  for (int e = 0; e < 16; ++e) {
    int i = tid + e * 256;
    xrow[i] = xload(x, (uint)255 * NN + (uint)i, x_cap);
  }
  __syncthreads();
#pragma unroll
  for (int m = 0; m < 16; ++m) {
    int s = tid + m * 256;
    if (s < NN - 1) {
      float a0 = 0.f;
      for (int i = 0; i < NN; ++i) {
        int t = s - i;
        float sgn = (t & 1) ? -0.63661977236758134f : 0.63661977236758134f;
        a0 = fmaf(xrow[i], __fdividef(sgn, (float)(2 * t + 1)), a0);
      }
      xio[s] = a0;
    }
  }
  __syncthreads();

  const int ty = tid >> 6, jj = tid & 63;
  const int j = j0 + jj;
  const int n = 2 * j - (NN - 1);
  const float base = fmaf(-L.q, (float)(n * n), L.pe);
  float acc = 0.f;
  int rend = (ty + 1) * 2048; if (rend > KK) rend = KK;
  for (int r = ty * 2048; r < rend; ++r) {
    int d = 2 * j - r;
    int k = r - (NN - 1);
    float ph = fmaf(L.c, (float)(d * d), fmaf(-L.q, (float)(k * k), base));
    float u = (r & 1) ? xio[r >> 1] : xrow[r >> 1];
    acc = fmaf(__cosf(ph), u, acc);
  }
  red[ty][jj] = acc;
  __syncthreads();
  if (ty == 0) {
    float t = red[0][jj] + red[1][jj] + red[2][jj] + red[3][jj];
    uint idx = (uint)255 * NN + (uint)j;
    if (idx < out_capf) out[idx] = L.scale * t;
  }
}

extern "C" void kernel_launch(void* const* d_in, const int* in_sizes, int n_in,
                              void* d_out, int out_size, void* d_ws, size_t ws_size,
                              hipStream_t stream) {
  const float* x     = (const float*)d_in[0];
  const float* order = (const float*)d_in[1];
  float* outf = (float*)d_out;
  const uint x_cap    = (uint)in_sizes[0];
  const uint out_capf = (uint)out_size;
  const size_t ws_halves = ws_size / 2;

  const size_t XIT_H = (size_t)NN * BB;          // 1,048,576 halves (2 MB)
  const size_t WPL_H = (size_t)4096 * 4096;      // 16,777,216 halves per plane

  // ---- R22 tier 1: precomputed-W path (needs ~69.2 MB ws) ----
  if (ws_size >= (XIT_H + 2 * WPL_H) * 2 &&
      out_capf >= (uint)NN * BB && x_cap >= (uint)NN * BB) {
    _Float16* xiT = (_Float16*)d_ws;
    _Float16* We  = xiT + XIT_H;
    _Float16* Wo  = We + WPL_H;
    wgen<<<dim3(512), 256, 0, stream>>>(order, We, Wo);
    s1_v4<<<dim3(256), 1024, 0, stream>>>(x, xiT);
    s2g<<<dim3(256), 1024, 0, stream>>>(x, xiT, We, Wo, order, outf);
    return;
  }

  // ---- R21 tier 2: in-loop-weight MFMA path (needs 2 MB ws) ----
  if (ws_size >= XIT_H * 2 &&
      out_capf >= (uint)NN * BB && x_cap >= (uint)NN * BB) {
    _Float16* xiT = (_Float16*)d_ws;
    s1_v4<<<dim3(256), 1024, 0, stream>>>(x, xiT);
    s2_v4<<<dim3(256), 1024, 0, stream>>>(x, xiT, order, outf);
    return;
  }

  // ---- R13 proven fallback paths ----
  if (ws_halves >= (size_t)(NN - 1) * BB) {
    uint xi_cap = (uint)((size_t)(NN - 1) * BB);
    frft_interp<<<dim3(64, 4), 256, 0, stream>>>(x, (__half*)d_ws, 0, BB, xi_cap, x_cap);
    frft_gemm<<<dim3(NN / TJ, BB / TB), 256, 0, stream>>>(x, (__half*)d_ws, order, outf,
                                                          0, BB, xi_cap, x_cap, out_capf);
  } else {
    struct Chunk { int lo, cnt; };
    const Chunk ch[6] = { {0,170}, {170,57}, {227,19}, {246,6}, {252,2}, {254,1} };
    for (int i = 0; i < 6; ++i) {
      const Chunk& c = ch[i];
      uint off = (uint)(c.lo + c.cnt) * (uint)NN;
      __half* xp = (__half*)(outf + off);
      size_t need = (size_t)(NN - 1) * (size_t)c.cnt;
      size_t avail = (out_capf > off) ? (size_t)(out_capf - off) * 2 : 0;
      uint xi_cap = (uint)(need < avail ? need : avail);
      frft_interp<<<dim3(64, (unsigned)((c.cnt + 63) / 64)), 256, 0, stream>>>(
          x, xp, c.lo, c.cnt, xi_cap, x_cap);
      frft_gemm<<<dim3(NN / TJ, (unsigned)((c.cnt + TB - 1) / TB)), 256, 0, stream>>>(
          x, xp, order, outf, c.lo, c.cnt, xi_cap, x_cap, out_capf);
    }
    if (ws_halves >= (size_t)(NN - 1)) {
      uint xi_cap = (uint)(NN - 1);
      frft_interp<<<dim3(64, 1), 256, 0, stream>>>(x, (__half*)d_ws, 255, 1, xi_cap, x_cap);
      frft_gemm<<<dim3(NN / TJ, 1), 256, 0, stream>>>(x, (__half*)d_ws, order, outf,
                                                      255, 1, xi_cap, x_cap, out_capf);
    } else {
      frft_gemm1<<<64, 256, 0, stream>>>(x, order, outf, x_cap, out_capf);
    }
  }
}

// Round 10
// 119.039 us; speedup vs baseline: 1.2257x; 1.2257x over previous
//
#include <hip/hip_runtime.h>
#include <hip/hip_fp16.h>
#include <math.h>

// FrFT (Ozaktas, 0.5<a<1.5): x[256,4096] f32, order f32 -> Re(complex64) f32
// out[b*4096+j]. R23: revert tier-1 (R9 showed the harness re-poisons ws
// proportional to dirtied bytes: 67 MB W-table -> 268 MB fill @48.6us/iter,
// a net loss). Keep the harvestable piece: one-time x->f16 conversion.
//   cvt_x: xh = f16(x) (pk2 RTZ, identical values to R8's in-loop staging
//   conversion), 2 MB. s1/s2 A-staging becomes pure u32x4 load + swizzled
//   ds_write (no per-chunk cvt, half the loads, -32 VGPR prefetch state).
//   Reduce: 8 kq-partials -> 4 planes in 2 rounds (5 barriers -> 3).
//   Total dirty ws = 4 MB -> re-poison stays negligible.
// Weight math byte-identical to proven R21/R8 (quadratic phase, __cosf,
// __fdividef, pkrtz pack); odd pad r=8191 weight-zeroed; LDS swizzle
// (gpos granule perm + row XOR) unchanged from the R8-proven layout.

#define NN 4096
#define BB 256
#define KK (2*NN - 1)
#define CHW 512

typedef unsigned int uint;
typedef __attribute__((ext_vector_type(4))) float f32x4;
typedef __attribute__((ext_vector_type(4))) uint u32x4;
typedef __attribute__((ext_vector_type(8))) _Float16 half8;
typedef __attribute__((ext_vector_type(4))) _Float16 half4;
typedef __attribute__((ext_vector_type(2))) __fp16 fp16x2;

struct LitConsts { float c, q, scale, pe; };

__device__ __forceinline__ LitConsts get_lit(const float* order) {
  float a = order[0];
  float alpha = a * (float)M_PI * 0.5f;
  float sina = sinf(alpha);
  float tana2 = tanf(alpha * 0.5f);
  LitConsts L;
  L.c = (float)M_PI / (float)NN / sina / 4.0f;
  L.q = ((float)M_PI / (float)NN) * (tana2 * 0.25f);
  L.scale = sqrtf(L.c / (float)M_PI);
  L.pe = -(1.0f - a) * (float)M_PI * 0.25f;
  return L;
}

__device__ __forceinline__ float xload(const float* __restrict__ x, uint idx, uint cap) {
  return (idx < cap) ? x[idx] : 0.f;
}

__device__ __forceinline__ uint pk2(float a, float b) {
  fp16x2 h = __builtin_amdgcn_cvt_pkrtz(a, b);
  return __builtin_bit_cast(uint, h);
}

__device__ __forceinline__ half8 pack8(const float* wv) {
  u32x4 u = { pk2(wv[0], wv[1]), pk2(wv[2], wv[3]),
              pk2(wv[4], wv[5]), pk2(wv[6], wv[7]) };
  return __builtin_bit_cast(half8, u);
}

// granule position permutation (16B granules within a 64-granule row)
__device__ __forceinline__ int gpos(int s) { return s ^ (s >> 3); }

// ---- one-time x -> f16 (RTZ, same values R8 staged in LDS) ----
__global__ __launch_bounds__(256) void cvt_x(const float* __restrict__ x,
                                             _Float16* __restrict__ xh) {
  const int g = blockIdx.x * 256 + threadIdx.x;      // granule id (8 f32 each)
  const f32x4* p = (const f32x4*)(x + (size_t)g * 8);
  f32x4 a = p[0], b = p[1];
  u32x4 d = { pk2(a[0], a[1]), pk2(a[2], a[3]), pk2(b[0], b[1]), pk2(b[2], b[3]) };
  *(u32x4*)(xh + (size_t)g * 8) = d;
}

// ---- stage 1: sinc interp GEMM; 256 blocks x 1024 thr; tile 64b x 64s ----
__global__ __launch_bounds__(1024, 4) void s1_v5(const _Float16* __restrict__ xh,
                                                 _Float16* __restrict__ xiT) {
  __shared__ __align__(16) _Float16 U[2][64][CHW];   // 128 KB
  float* redf = (float*)&U[0][0][0];                 // aliased after k-loop
  const int tid = threadIdx.x;
  const int w = tid >> 6, lane = tid & 63;
  const int l15 = lane & 15, lhi = lane >> 4;
  const int kq = w & 7, fh = w >> 3;
  const int id = blockIdx.x, xcd = id & 7;
  const int b0 = (xcd >> 1) * 64;                    // same-b blocks -> XCD
  const int s0 = ((xcd & 1) | ((id >> 3) << 1)) * 64;
  const int srow = tid >> 4, t15 = tid & 15;
  const int swz = (srow & 7) << 4;
  const float C2PI = 0.63661977236758134f;

  const _Float16* xrow = xh + (size_t)(b0 + srow) * NN;

  f32x4 acc[4][2] = {};
  u32x4 po[4];

  { // prologue: stage chunk 0
#pragma unroll
    for (int k = 0; k < 4; ++k)
      po[k] = *(const u32x4*)(xrow + (t15 + 16 * k) * 8);
    char* base = (char*)&U[0][srow][0];
#pragma unroll
    for (int k = 0; k < 4; ++k) {
      const int s = t15 + 16 * k;
      *(u32x4*)(base + ((gpos(s) << 4) ^ swz)) = po[k];
    }
  }

  for (int ch = 0; ch < 8; ++ch) {
    __syncthreads();
    const int cb = ch & 1;
    if (ch < 7) {
#pragma unroll
      for (int k = 0; k < 4; ++k)
        po[k] = *(const u32x4*)(xrow + (ch + 1) * CHW + (t15 + 16 * k) * 8);
    }
#pragma unroll
    for (int st = 0; st < 2; ++st) {
      const int sg = kq * 8 + st * 4 + lhi;
      const int go = gpos(sg) << 4;
      half8 af[4];
#pragma unroll
      for (int fm = 0; fm < 4; ++fm) {
        const int row = fm * 16 + l15;
        af[fm] = *(const half8*)((const char*)&U[cb][row][0] + (go ^ ((row & 7) << 4)));
      }
      const int i0 = ch * CHW + kq * 64 + st * 32 + lhi * 8;
#pragma unroll
      for (int g = 0; g < 2; ++g) {
        const int t0 = (s0 + (fh * 2 + g) * 16 + l15) - i0;
        float wv[8];
#pragma unroll
        for (int e = 0; e < 8; ++e) {
          const int t = t0 - e;
          const float sgn = (t & 1) ? -C2PI : C2PI;
          wv[e] = __fdividef(sgn, (float)(2 * t + 1));
        }
        const half8 bh = pack8(wv);
#pragma unroll
        for (int fm = 0; fm < 4; ++fm)
          acc[fm][g] = __builtin_amdgcn_mfma_f32_16x16x32_f16(af[fm], bh, acc[fm][g], 0, 0, 0);
      }
    }
    if (ch < 7) {
      char* base = (char*)&U[cb ^ 1][srow][0];
#pragma unroll
      for (int k = 0; k < 4; ++k) {
        const int s = t15 + 16 * k;
        *(u32x4*)(base + ((gpos(s) << 4) ^ swz)) = po[k];
      }
    }
  }

  // 8 kq-partials -> 4 red planes (aliased over U) in 2 rounds
  __syncthreads();
  if (kq < 4) {
#pragma unroll
    for (int fm = 0; fm < 4; ++fm)
#pragma unroll
      for (int g = 0; g < 2; ++g)
#pragma unroll
        for (int rr = 0; rr < 4; ++rr)
          redf[((kq * 64) + fm * 16 + lhi * 4 + rr) * 68 + (fh * 2 + g) * 16 + l15] =
              acc[fm][g][rr];
  }
  __syncthreads();
  if (kq >= 4) {
#pragma unroll
    for (int fm = 0; fm < 4; ++fm)
#pragma unroll
      for (int g = 0; g < 2; ++g)
#pragma unroll
        for (int rr = 0; rr < 4; ++rr)
          redf[(((kq - 4) * 64) + fm * 16 + lhi * 4 + rr) * 68 + (fh * 2 + g) * 16 + l15] +=
              acc[fm][g][rr];
  }
  __syncthreads();

  const int c0 = t15 * 4;
  half4 h;
#pragma unroll
  for (int e = 0; e < 4; ++e)
    h[e] = (_Float16)(redf[(srow) * 68 + c0 + e] + redf[(64 + srow) * 68 + c0 + e] +
                      redf[(128 + srow) * 68 + c0 + e] + redf[(192 + srow) * 68 + c0 + e]);
  *(half4*)(xiT + (size_t)(b0 + srow) * NN + s0 + c0) = h;
}

// ---- stage 2: fused even+odd chirp GEMM; 256 blocks x 1024 thr ----
__global__ __launch_bounds__(1024, 4) void s2_v5(const _Float16* __restrict__ xh,
                                                 const _Float16* __restrict__ xiT,
                                                 const float* __restrict__ order,
                                                 float* __restrict__ out) {
  __shared__ __align__(16) _Float16 U[2][64][CHW];
  float* redf = (float*)&U[0][0][0];
  const int tid = threadIdx.x;
  const int w = tid >> 6, lane = tid & 63;
  const int l15 = lane & 15, lhi = lane >> 4;
  const int kq = w & 7, fh = w >> 3;
  const int id = blockIdx.x, xcd = id & 7;
  const int b0 = (xcd >> 1) * 64;
  const int j0 = ((xcd & 1) | ((id >> 3) << 1)) * 64;
  const int srow = tid >> 4, t15 = tid & 15;
  const int swz = (srow & 7) << 4;

  const LitConsts L = get_lit(order);
  const float P2 = 4.f * (L.c - L.q);
  int jl[2]; float jbase[2];
#pragma unroll
  for (int g = 0; g < 2; ++g) {
    jl[g] = j0 + (fh * 2 + g) * 16 + l15;
    const int n = 2 * jl[g] - (NN - 1);
    jbase[g] = fmaf(-L.q, (float)(n * n), L.pe);
  }

  const _Float16* xrow = xh + (size_t)(b0 + srow) * NN;
  const _Float16* orow = xiT + (size_t)(b0 + srow) * NN;

  f32x4 acc[4][2] = {};
  u32x4 po[4];

  { // prologue: stage even chunk 0
#pragma unroll
    for (int k = 0; k < 4; ++k)
      po[k] = *(const u32x4*)(xrow + (t15 + 16 * k) * 8);
    char* base = (char*)&U[0][srow][0];
#pragma unroll
    for (int k = 0; k < 4; ++k) {
      const int s = t15 + 16 * k;
      *(u32x4*)(base + ((gpos(s) << 4) ^ swz)) = po[k];
    }
  }

  // EVEN pass (r = 2i, A from xh); ch=7 prefetches odd chunk 0 from xiT
  for (int ch = 0; ch < 8; ++ch) {
    __syncthreads();
    const int cb = ch & 1;
    {
      const _Float16* src = (ch < 7) ? (xrow + (ch + 1) * CHW) : orow;
#pragma unroll
      for (int k = 0; k < 4; ++k)
        po[k] = *(const u32x4*)(src + (t15 + 16 * k) * 8);
    }
#pragma unroll
    for (int st = 0; st < 2; ++st) {
      const int sg = kq * 8 + st * 4 + lhi;
      const int go = gpos(sg) << 4;
      half8 af[4];
#pragma unroll
      for (int fm = 0; fm < 4; ++fm) {
        const int row = fm * 16 + l15;
        af[fm] = *(const half8*)((const char*)&U[cb][row][0] + (go ^ ((row & 7) << 4)));
      }
      const int i0 = ch * CHW + kq * 64 + st * 32 + lhi * 8;
      const int r0 = 2 * i0;
      const int k0 = r0 - (NN - 1);
      const float bk  = -L.q * (float)(k0 * k0);
      const float qk0 =  L.q * (float)k0;
#pragma unroll
      for (int g = 0; g < 2; ++g) {
        const int d0 = 2 * jl[g] - r0;
        const float P0 = fmaf(L.c, (float)(d0 * d0), jbase[g] + bk);
        const float P1 = -4.f * fmaf(L.c, (float)d0, qk0);
        float wv[8];
#pragma unroll
        for (int e = 0; e < 8; ++e) {
          const float ef = (float)e;
          wv[e] = __cosf(fmaf(ef, fmaf(ef, P2, P1), P0));
        }
        const half8 bh = pack8(wv);
#pragma unroll
        for (int fm = 0; fm < 4; ++fm)
          acc[fm][g] = __builtin_amdgcn_mfma_f32_16x16x32_f16(af[fm], bh, acc[fm][g], 0, 0, 0);
      }
    }
    {
      char* base = (char*)&U[cb ^ 1][srow][0];
#pragma unroll
      for (int k = 0; k < 4; ++k) {
        const int s = t15 + 16 * k;
        *(u32x4*)(base + ((gpos(s) << 4) ^ swz)) = po[k];
      }
    }
  }

  // ODD pass (r = 2i+1, A from xiT); odd chunk 0 already in U[0]
  for (int ch = 0; ch < 8; ++ch) {
    __syncthreads();
    const int cb = ch & 1;
    if (ch < 7) {
#pragma unroll
      for (int k = 0; k < 4; ++k)
        po[k] = *(const u32x4*)(orow + (ch + 1) * CHW + (t15 + 16 * k) * 8);
    }
#pragma unroll
    for (int st = 0; st < 2; ++st) {
      const int sg = kq * 8 + st * 4 + lhi;
      const int go = gpos(sg) << 4;
      half8 af[4];
#pragma unroll
      for (int fm = 0; fm < 4; ++fm) {
        const int row = fm * 16 + l15;
        af[fm] = *(const half8*)((const char*)&U[cb][row][0] + (go ^ ((row & 7) << 4)));
      }
      const int i0 = ch * CHW + kq * 64 + st * 32 + lhi * 8;
      const int r0 = 2 * i0 + 1;
      const int k0 = r0 - (NN - 1);
      const float bk  = -L.q * (float)(k0 * k0);
      const float qk0 =  L.q * (float)k0;
#pragma unroll
      for (int g = 0; g < 2; ++g) {
        const int d0 = 2 * jl[g] - r0;
        const float P0 = fmaf(L.c, (float)(d0 * d0), jbase[g] + bk);
        const float P1 = -4.f * fmaf(L.c, (float)d0, qk0);
        float wv[8];
#pragma unroll
        for (int e = 0; e < 8; ++e) {
          const float ef = (float)e;
          float t = __cosf(fmaf(ef, fmaf(ef, P2, P1), P0));
          if (i0 + e > NN - 2) t = 0.f;   // r=8191 pad does not exist
          wv[e] = t;
        }
        const half8 bh = pack8(wv);
#pragma unroll
        for (int fm = 0; fm < 4; ++fm)
          acc[fm][g] = __builtin_amdgcn_mfma_f32_16x16x32_f16(af[fm], bh, acc[fm][g], 0, 0, 0);
      }
    }
    if (ch < 7) {
      char* base = (char*)&U[cb ^ 1][srow][0];
#pragma unroll
      for (int k = 0; k < 4; ++k) {
        const int s = t15 + 16 * k;
        *(u32x4*)(base + ((gpos(s) << 4) ^ swz)) = po[k];
      }
    }
  }

  // 8 kq-partials -> 4 red planes in 2 rounds + scaled store
  __syncthreads();
  if (kq < 4) {
#pragma unroll
    for (int fm = 0; fm < 4; ++fm)
#pragma unroll
      for (int g = 0; g < 2; ++g)
#pragma unroll
        for (int rr = 0; rr < 4; ++rr)
          redf[((kq * 64) + fm * 16 + lhi * 4 + rr) * 68 + (fh * 2 + g) * 16 + l15] =
              acc[fm][g][rr];
  }
  __syncthreads();
  if (kq >= 4) {
#pragma unroll
    for (int fm = 0; fm < 4; ++fm)
#pragma unroll
      for (int g = 0; g < 2; ++g)
#pragma unroll
        for (int rr = 0; rr < 4; ++rr)
          redf[(((kq - 4) * 64) + fm * 16 + lhi * 4 + rr) * 68 + (fh * 2 + g) * 16 + l15] +=
              acc[fm][g][rr];
  }
  __syncthreads();

  const int c0 = t15 * 4;
  f32x4 v;
#pragma unroll
  for (int e = 0; e < 4; ++e)
    v[e] = L.scale * (redf[(srow) * 68 + c0 + e] + redf[(64 + srow) * 68 + c0 + e] +
                      redf[(128 + srow) * 68 + c0 + e] + redf[(192 + srow) * 68 + c0 + e]);
  *(f32x4*)(out + (size_t)(b0 + srow) * NN + j0 + c0) = v;
}

// ======================= R13 proven fallback (small ws) =======================

__global__ __launch_bounds__(256) void frft_interp(const float* __restrict__ x,
                                                   __half* __restrict__ xi,
                                                   int b_lo, int cnt,
                                                   uint xi_cap, uint x_cap) {
  __shared__ __align__(16) float wt1[32][64];
  __shared__ __align__(16) float xt[32][64];
  const int tid = threadIdx.x;
  const int s0 = blockIdx.x * 64, cb0 = blockIdx.y * 64;
  const int tx = tid & 15, ty = tid >> 4;
  const int ss0 = ty * 4, bb0 = tx * 4;

  float acc[4][4] = {};
  for (int i0 = 0; i0 < NN; i0 += 32) {
#pragma unroll
    for (int e = 0; e < 8; ++e) {
      int idx = tid + e * 256, qq = idx >> 6, ss = idx & 63;
      int t = s0 + ss - (i0 + qq);
      float sgn = (t & 1) ? -0.63661977236758134f : 0.63661977236758134f;
      wt1[qq][ss] = __fdividef(sgn, (float)(2 * t + 1));
    }
#pragma unroll
    for (int e = 0; e < 8; ++e) {
      int idx = tid + e * 256, qq = idx >> 6, bb = idx & 63;
      xt[qq][bb] = xload(x, (uint)(b_lo + cb0 + bb) * NN + (i0 + qq), x_cap);
    }
    __syncthreads();
#pragma unroll
    for (int qq = 0; qq < 32; ++qq) {
      float4 wv = *(const float4*)&wt1[qq][ss0];
      float4 uv = *(const float4*)&xt[qq][bb0];
      float w[4] = {wv.x, wv.y, wv.z, wv.w};
      float u[4] = {uv.x, uv.y, uv.z, uv.w};
#pragma unroll
      for (int aa = 0; aa < 4; ++aa)
#pragma unroll
        for (int cc = 0; cc < 4; ++cc) acc[aa][cc] = fmaf(w[aa], u[cc], acc[aa][cc]);
    }
    __syncthreads();
  }
#pragma unroll
  for (int aa = 0; aa < 4; ++aa) {
    int s = s0 + ss0 + aa;
    if (s < NN - 1) {
#pragma unroll
      for (int cc = 0; cc < 4; ++cc) {
        int cb = cb0 + bb0 + cc;
        if (cb < cnt) {
          uint o = (uint)s * (uint)cnt + (uint)cb;
          if (o < xi_cap) xi[o] = __float2half(acc[aa][cc]);
        }
      }
    }
  }
}

#define TJ 32
#define TB 64
#define TK 32
__global__ __launch_bounds__(256) void frft_gemm(const float* __restrict__ x,
                                                 const __half* __restrict__ xi,
                                                 const float* __restrict__ order,
                                                 float* __restrict__ out,
                                                 int b_lo, int cnt,
                                                 uint xi_cap, uint x_cap,
                                                 uint out_capf) {
  __shared__ __align__(16) float wt[TK][TJ];
  __shared__ __align__(16) float ut[TK][TB];
  const int tid = threadIdx.x;
  const int j0 = blockIdx.x * TJ, cb0 = blockIdx.y * TB;
  const int tx = tid & 15, ty = tid >> 4;
  const int jj0 = ty * 2, bb0 = tx * 4;

  LitConsts L = get_lit(order);
  float acc[2][4] = {};

  for (int r0 = 0; r0 < KK; r0 += TK) {
#pragma unroll
    for (int e = 0; e < 4; ++e) {
      int idx = tid + e * 256, qq = idx >> 5, jj = idx & 31;
      int r = r0 + qq;
      float wv = 0.f;
      if (r < KK) {
        int j = j0 + jj;
        int n = 2 * j - (NN - 1);
        int d = 2 * j - r;
        int k = r - (NN - 1);
        float base = fmaf(-L.q, (float)(n * n), L.pe);
        float ph = fmaf(L.c, (float)(d * d), fmaf(-L.q, (float)(k * k), base));
        wv = __cosf(ph);
      }
      wt[qq][jj] = wv;
    }
#pragma unroll
    for (int e = 0; e < 8; ++e) {
      int idx = tid + e * 256, qq = idx >> 6, bb = idx & 63;
      int r = r0 + qq, cb = cb0 + bb;
      float v = 0.f;
      if (r < KK && cb < cnt) {
        if (r & 1) {
          uint o = (uint)(r >> 1) * (uint)cnt + (uint)cb;
          v = (o < xi_cap) ? __half2float(xi[o]) : 0.f;
        } else {
          v = xload(x, (uint)(b_lo + cb) * NN + (uint)(r >> 1), x_cap);
        }
      }
      ut[qq][bb] = v;
    }
    __syncthreads();
#pragma unroll
    for (int qq = 0; qq < TK; ++qq) {
      float2 wv = *(const float2*)&wt[qq][jj0];
      float4 uv = *(const float4*)&ut[qq][bb0];
      float w[2] = {wv.x, wv.y};
      float u[4] = {uv.x, uv.y, uv.z, uv.w};
#pragma unroll
      for (int aa = 0; aa < 2; ++aa)
#pragma unroll
        for (int cc = 0; cc < 4; ++cc)
          acc[aa][cc] = fmaf(w[aa], u[cc], acc[aa][cc]);
    }
    __syncthreads();
  }

#pragma unroll
  for (int aa = 0; aa < 2; ++aa) {
    int j = j0 + jj0 + aa;
#pragma unroll
    for (int cc = 0; cc < 4; ++cc) {
      int cb = cb0 + bb0 + cc;
      if (cb < cnt) {
        uint idx = (uint)(b_lo + cb) * NN + (uint)j;
        if (idx < out_capf) out[idx] = L.scale * acc[aa][cc];
      }
    }
  }
}

__global__ __launch_bounds__(256) void frft_gemm1(const float* __restrict__ x,
                                                  const float* __restrict__ order,
                                                  float* __restrict__ out,
                                                  uint x_cap, uint out_capf) {
  __shared__ float xrow[NN];
  __shared__ float xio[NN - 1];
  __shared__ float red[4][64];
  const int tid = threadIdx.x;
  const int j0 = blockIdx.x * 64;
  LitConsts L = get_lit(order);

#pragma unroll
  for (int e = 0; e < 16; ++e) {
    int i = tid + e * 256;
    xrow[i] = xload(x, (uint)255 * NN + (uint)i, x_cap);
  }
  __syncthreads();
#pragma unroll
  for (int m = 0; m < 16; ++m) {
    int s = tid + m * 256;
    if (s < NN - 1) {
      float a0 = 0.f;
      for (int i = 0; i < NN; ++i) {
        int t = s - i;
        float sgn = (t & 1) ? -0.63661977236758134f : 0.63661977236758134f;
        a0 = fmaf(xrow[i], __fdividef(sgn, (float)(2 * t + 1)), a0);
      }
      xio[s] = a0;
    }
  }
  __syncthreads();

  const int ty = tid >> 6, jj = tid & 63;
  const int j = j0 + jj;
  const int n = 2 * j - (NN - 1);
  const float base = fmaf(-L.q, (float)(n * n), L.pe);
  float acc = 0.f;
  int rend = (ty + 1) * 2048; if (rend > KK) rend = KK;
  for (int r = ty * 2048; r < rend; ++r) {
    int d = 2 * j - r;
    int k = r - (NN - 1);
    float ph = fmaf(L.c, (float)(d * d), fmaf(-L.q, (float)(k * k), base));
    float u = (r & 1) ? xio[r >> 1] : xrow[r >> 1];
    acc = fmaf(__cosf(ph), u, acc);
  }
  red[ty][jj] = acc;
  __syncthreads();
  if (ty == 0) {
    float t = red[0][jj] + red[1][jj] + red[2][jj] + red[3][jj];
    uint idx = (uint)255 * NN + (uint)j;
    if (idx < out_capf) out[idx] = L.scale * t;
  }
}

extern "C" void kernel_launch(void* const* d_in, const int* in_sizes, int n_in,
                              void* d_out, int out_size, void* d_ws, size_t ws_size,
                              hipStream_t stream) {
  const float* x     = (const float*)d_in[0];
  const float* order = (const float*)d_in[1];
  float* outf = (float*)d_out;
  const uint x_cap    = (uint)in_sizes[0];
  const uint out_capf = (uint)out_size;
  const size_t ws_halves = ws_size / 2;

  const size_t XIT_H = (size_t)NN * BB;   // 1,048,576 halves (2 MB)

  // ---- R23 path: xiT (2 MB) + xh (2 MB) in ws; small dirty footprint ----
  if (ws_size >= XIT_H * 2 * 2 &&
      out_capf >= (uint)NN * BB && x_cap >= (uint)NN * BB) {
    _Float16* xiT = (_Float16*)d_ws;
    _Float16* xh  = xiT + XIT_H;
    cvt_x<<<dim3(512), 256, 0, stream>>>(x, xh);
    s1_v5<<<dim3(256), 1024, 0, stream>>>(xh, xiT);
    s2_v5<<<dim3(256), 1024, 0, stream>>>(xh, xiT, order, outf);
    return;
  }

  // ---- R13 proven fallback paths ----
  if (ws_halves >= (size_t)(NN - 1) * BB) {
    uint xi_cap = (uint)((size_t)(NN - 1) * BB);
    frft_interp<<<dim3(64, 4), 256, 0, stream>>>(x, (__half*)d_ws, 0, BB, xi_cap, x_cap);
    frft_gemm<<<dim3(NN / TJ, BB / TB), 256, 0, stream>>>(x, (__half*)d_ws, order, outf,
                                                          0, BB, xi_cap, x_cap, out_capf);
  } else {
    struct Chunk { int lo, cnt; };
    const Chunk ch[6] = { {0,170}, {170,57}, {227,19}, {246,6}, {252,2}, {254,1} };
    for (int i = 0; i < 6; ++i) {
      const Chunk& c = ch[i];
      uint off = (uint)(c.lo + c.cnt) * (uint)NN;
      __half* xp = (__half*)(outf + off);
      size_t need = (size_t)(NN - 1) * (size_t)c.cnt;
      size_t avail = (out_capf > off) ? (size_t)(out_capf - off) * 2 : 0;
      uint xi_cap = (uint)(need < avail ? need : avail);
      frft_interp<<<dim3(64, (unsigned)((c.cnt + 63) / 64)), 256, 0, stream>>>(
          x, xp, c.lo, c.cnt, xi_cap, x_cap);
      frft_gemm<<<dim3(NN / TJ, (unsigned)((c.cnt + TB - 1) / TB)), 256, 0, stream>>>(
          x, xp, order, outf, c.lo, c.cnt, xi_cap, x_cap, out_capf);
    }
    if (ws_halves >= (size_t)(NN - 1)) {
      uint xi_cap = (uint)(NN - 1);
      frft_interp<<<dim3(64, 1), 256, 0, stream>>>(x, (__half*)d_ws, 255, 1, xi_cap, x_cap);
      frft_gemm<<<dim3(NN / TJ, 1), 256, 0, stream>>>(x, (__half*)d_ws, order, outf,
                                                      255, 1, xi_cap, x_cap, out_capf);
    } else {
      frft_gemm1<<<64, 256, 0, stream>>>(x, order, outf, x_cap, out_capf);
    }
  }
}

// Round 11
// 115.446 us; speedup vs baseline: 1.2638x; 1.0311x over previous
//
#include <hip/hip_runtime.h>
#include <hip/hip_fp16.h>
#include <math.h>

// FrFT (Ozaktas, 0.5<a<1.5): x[256,4096] f32, order f32 -> Re(complex64) f32
// out[b*4096+j]. R24: two VALU cuts on the R23 structure.
//   R10 facts: 268MB fill = harness's UNCONDITIONAL ws re-poison (~41us fixed
//   floor, present every round); our kernels = cvt 1.5 + s1 35.7 + s2 40.8.
//   (1) s2 rev-phase: quadratic phase computed in REVOLUTIONS (constants
//       pre-scaled by 1/2pi), cos via v_fract+v_cos builtins -> deletes
//       __cosf's internal mul (134M lane-ops). Phase err 7.7e-4 rad <
//       f16 weight quantization -> same error class.
//   (2) s1 Toeplitz shift-reuse: wave frags at s-offsets {fh*16, fh*16+32};
//       i0 steps 32 between st0->st1 so frag_g1(st1) == frag_g0(st0)
//       bit-identically -> 3 fresh frags/chunk instead of 4 (-25% rcp).
// Everything else (LDS swizzle, staging, reduce, cvt_x, fallbacks) is the
// R23-proven structure unchanged. Odd pad r=8191 weight-zeroed.

#define NN 4096
#define BB 256
#define KK (2*NN - 1)
#define CHW 512

typedef unsigned int uint;
typedef __attribute__((ext_vector_type(4))) float f32x4;
typedef __attribute__((ext_vector_type(4))) uint u32x4;
typedef __attribute__((ext_vector_type(8))) _Float16 half8;
typedef __attribute__((ext_vector_type(4))) _Float16 half4;
typedef __attribute__((ext_vector_type(2))) __fp16 fp16x2;

struct LitConsts { float c, q, scale, pe; };

__device__ __forceinline__ LitConsts get_lit(const float* order) {
  float a = order[0];
  float alpha = a * (float)M_PI * 0.5f;
  float sina = sinf(alpha);
  float tana2 = tanf(alpha * 0.5f);
  LitConsts L;
  L.c = (float)M_PI / (float)NN / sina / 4.0f;
  L.q = ((float)M_PI / (float)NN) * (tana2 * 0.25f);
  L.scale = sqrtf(L.c / (float)M_PI);
  L.pe = -(1.0f - a) * (float)M_PI * 0.25f;
  return L;
}

__device__ __forceinline__ float xload(const float* __restrict__ x, uint idx, uint cap) {
  return (idx < cap) ? x[idx] : 0.f;
}

__device__ __forceinline__ uint pk2(float a, float b) {
  fp16x2 h = __builtin_amdgcn_cvt_pkrtz(a, b);
  return __builtin_bit_cast(uint, h);
}

__device__ __forceinline__ half8 pack8(const float* wv) {
  u32x4 u = { pk2(wv[0], wv[1]), pk2(wv[2], wv[3]),
              pk2(wv[4], wv[5]), pk2(wv[6], wv[7]) };
  return __builtin_bit_cast(half8, u);
}

// granule position permutation (16B granules within a 64-granule row)
__device__ __forceinline__ int gpos(int s) { return s ^ (s >> 3); }

// sinc Toeplitz weight fragment: elements e=0..7 at t = t0 - e (R13-proven math)
__device__ __forceinline__ half8 mkw1(int t0) {
  const float C2PI = 0.63661977236758134f;
  float wv[8];
#pragma unroll
  for (int e = 0; e < 8; ++e) {
    const int t = t0 - e;
    const float sgn = (t & 1) ? -C2PI : C2PI;
    wv[e] = __fdividef(sgn, (float)(2 * t + 1));
  }
  return pack8(wv);
}

// ---- one-time x -> f16 (RTZ, same values R8 staged in LDS) ----
__global__ __launch_bounds__(256) void cvt_x(const float* __restrict__ x,
                                             _Float16* __restrict__ xh) {
  const int g = blockIdx.x * 256 + threadIdx.x;      // granule id (8 f32 each)
  const f32x4* p = (const f32x4*)(x + (size_t)g * 8);
  f32x4 a = p[0], b = p[1];
  u32x4 d = { pk2(a[0], a[1]), pk2(a[2], a[3]), pk2(b[0], b[1]), pk2(b[2], b[3]) };
  *(u32x4*)(xh + (size_t)g * 8) = d;
}

// ---- stage 1: sinc interp GEMM; 256 blocks x 1024 thr; tile 64b x 64s ----
// Wave frags at s-offsets {fh*16, fh*16+32}; frag_g1(st1) == frag_g0(st0).
__global__ __launch_bounds__(1024, 4) void s1_v6(const _Float16* __restrict__ xh,
                                                 _Float16* __restrict__ xiT) {
  __shared__ __align__(16) _Float16 U[2][64][CHW];   // 128 KB
  float* redf = (float*)&U[0][0][0];                 // aliased after k-loop
  const int tid = threadIdx.x;
  const int w = tid >> 6, lane = tid & 63;
  const int l15 = lane & 15, lhi = lane >> 4;
  const int kq = w & 7, fh = w >> 3;
  const int id = blockIdx.x, xcd = id & 7;
  const int b0 = (xcd >> 1) * 64;                    // same-b blocks -> XCD
  const int s0 = ((xcd & 1) | ((id >> 3) << 1)) * 64;
  const int srow = tid >> 4, t15 = tid & 15;
  const int swz = (srow & 7) << 4;

  const _Float16* xrow = xh + (size_t)(b0 + srow) * NN;

  f32x4 acc[4][2] = {};   // [fm][g]; g=0 -> s-off fh*16, g=1 -> fh*16+32
  u32x4 po[4];

  { // prologue: stage chunk 0
#pragma unroll
    for (int k = 0; k < 4; ++k)
      po[k] = *(const u32x4*)(xrow + (t15 + 16 * k) * 8);
    char* base = (char*)&U[0][srow][0];
#pragma unroll
    for (int k = 0; k < 4; ++k) {
      const int s = t15 + 16 * k;
      *(u32x4*)(base + ((gpos(s) << 4) ^ swz)) = po[k];
    }
  }

  for (int ch = 0; ch < 8; ++ch) {
    __syncthreads();
    const int cb = ch & 1;
    if (ch < 7) {
#pragma unroll
      for (int k = 0; k < 4; ++k)
        po[k] = *(const u32x4*)(xrow + (ch + 1) * CHW + (t15 + 16 * k) * 8);
    }
    const int i00 = ch * CHW + kq * 64 + lhi * 8;    // st = 0 k-base
    const int t00 = (s0 + fh * 16 + l15) - i00;      // g0 @ st0
    half8 keep;                                      // frag reused at st1/g1
    // ---- st = 0 ----
    {
      const int sg = kq * 8 + lhi;
      const int go = gpos(sg) << 4;
      half8 af[4];
#pragma unroll
      for (int fm = 0; fm < 4; ++fm) {
        const int row = fm * 16 + l15;
        af[fm] = *(const half8*)((const char*)&U[cb][row][0] + (go ^ ((row & 7) << 4)));
      }
      keep = mkw1(t00);                              // fresh g0
      const half8 bh1 = mkw1(t00 + 32);              // fresh g1
#pragma unroll
      for (int fm = 0; fm < 4; ++fm) {
        acc[fm][0] = __builtin_amdgcn_mfma_f32_16x16x32_f16(af[fm], keep, acc[fm][0], 0, 0, 0);
        acc[fm][1] = __builtin_amdgcn_mfma_f32_16x16x32_f16(af[fm], bh1, acc[fm][1], 0, 0, 0);
      }
    }
    // ---- st = 1 (i0 += 32): g1 reuses st0's g0 frag bit-identically ----
    {
      const int sg = kq * 8 + 4 + lhi;
      const int go = gpos(sg) << 4;
      half8 af[4];
#pragma unroll
      for (int fm = 0; fm < 4; ++fm) {
        const int row = fm * 16 + l15;
        af[fm] = *(const half8*)((const char*)&U[cb][row][0] + (go ^ ((row & 7) << 4)));
      }
      const half8 bh0 = mkw1(t00 - 32);              // fresh g0
#pragma unroll
      for (int fm = 0; fm < 4; ++fm) {
        acc[fm][0] = __builtin_amdgcn_mfma_f32_16x16x32_f16(af[fm], bh0, acc[fm][0], 0, 0, 0);
        acc[fm][1] = __builtin_amdgcn_mfma_f32_16x16x32_f16(af[fm], keep, acc[fm][1], 0, 0, 0);
      }
    }
    if (ch < 7) {
      char* base = (char*)&U[cb ^ 1][srow][0];
#pragma unroll
      for (int k = 0; k < 4; ++k) {
        const int s = t15 + 16 * k;
        *(u32x4*)(base + ((gpos(s) << 4) ^ swz)) = po[k];
      }
    }
  }

  // 8 kq-partials -> 4 red planes (aliased over U) in 2 rounds
  __syncthreads();
  if (kq < 4) {
#pragma unroll
    for (int fm = 0; fm < 4; ++fm)
#pragma unroll
      for (int g = 0; g < 2; ++g)
#pragma unroll
        for (int rr = 0; rr < 4; ++rr)
          redf[((kq * 64) + fm * 16 + lhi * 4 + rr) * 68 + fh * 16 + g * 32 + l15] =
              acc[fm][g][rr];
  }
  __syncthreads();
  if (kq >= 4) {
#pragma unroll
    for (int fm = 0; fm < 4; ++fm)
#pragma unroll
      for (int g = 0; g < 2; ++g)
#pragma unroll
        for (int rr = 0; rr < 4; ++rr)
          redf[(((kq - 4) * 64) + fm * 16 + lhi * 4 + rr) * 68 + fh * 16 + g * 32 + l15] +=
              acc[fm][g][rr];
  }
  __syncthreads();

  const int c0 = t15 * 4;
  half4 h;
#pragma unroll
  for (int e = 0; e < 4; ++e)
    h[e] = (_Float16)(redf[(srow) * 68 + c0 + e] + redf[(64 + srow) * 68 + c0 + e] +
                      redf[(128 + srow) * 68 + c0 + e] + redf[(192 + srow) * 68 + c0 + e]);
  *(half4*)(xiT + (size_t)(b0 + srow) * NN + s0 + c0) = h;
}

// ---- stage 2: fused even+odd chirp GEMM; rev-unit phases; 256 x 1024 ----
__global__ __launch_bounds__(1024, 4) void s2_v6(const _Float16* __restrict__ xh,
                                                 const _Float16* __restrict__ xiT,
                                                 const float* __restrict__ order,
                                                 float* __restrict__ out) {
  __shared__ __align__(16) _Float16 U[2][64][CHW];
  float* redf = (float*)&U[0][0][0];
  const int tid = threadIdx.x;
  const int w = tid >> 6, lane = tid & 63;
  const int l15 = lane & 15, lhi = lane >> 4;
  const int kq = w & 7, fh = w >> 3;
  const int id = blockIdx.x, xcd = id & 7;
  const int b0 = (xcd >> 1) * 64;
  const int j0 = ((xcd & 1) | ((id >> 3) << 1)) * 64;
  const int srow = tid >> 4, t15 = tid & 15;
  const int swz = (srow & 7) << 4;

  const LitConsts L = get_lit(order);
  // revolution-unit constants: phase_rev = phase_rad / 2pi
  const float I2P = 0.15915494309189535f;
  const float cr = L.c * I2P, qr = L.q * I2P, per_ = L.pe * I2P;
  const float P2r = 4.f * (cr - qr);
  int jl[2]; float jbase[2];
#pragma unroll
  for (int g = 0; g < 2; ++g) {
    jl[g] = j0 + (fh * 2 + g) * 16 + l15;
    const int n = 2 * jl[g] - (NN - 1);
    jbase[g] = fmaf(-qr, (float)(n * n), per_);
  }

  const _Float16* xrow = xh + (size_t)(b0 + srow) * NN;
  const _Float16* orow = xiT + (size_t)(b0 + srow) * NN;

  f32x4 acc[4][2] = {};
  u32x4 po[4];

  { // prologue: stage even chunk 0
#pragma unroll
    for (int k = 0; k < 4; ++k)
      po[k] = *(const u32x4*)(xrow + (t15 + 16 * k) * 8);
    char* base = (char*)&U[0][srow][0];
#pragma unroll
    for (int k = 0; k < 4; ++k) {
      const int s = t15 + 16 * k;
      *(u32x4*)(base + ((gpos(s) << 4) ^ swz)) = po[k];
    }
  }

  // EVEN pass (r = 2i, A from xh); ch=7 prefetches odd chunk 0 from xiT
  for (int ch = 0; ch < 8; ++ch) {
    __syncthreads();
    const int cb = ch & 1;
    {
      const _Float16* src = (ch < 7) ? (xrow + (ch + 1) * CHW) : orow;
#pragma unroll
      for (int k = 0; k < 4; ++k)
        po[k] = *(const u32x4*)(src + (t15 + 16 * k) * 8);
    }
#pragma unroll
    for (int st = 0; st < 2; ++st) {
      const int sg = kq * 8 + st * 4 + lhi;
      const int go = gpos(sg) << 4;
      half8 af[4];
#pragma unroll
      for (int fm = 0; fm < 4; ++fm) {
        const int row = fm * 16 + l15;
        af[fm] = *(const half8*)((const char*)&U[cb][row][0] + (go ^ ((row & 7) << 4)));
      }
      const int i0 = ch * CHW + kq * 64 + st * 32 + lhi * 8;
      const int r0 = 2 * i0;
      const int k0 = r0 - (NN - 1);
      const float bk  = -qr * (float)(k0 * k0);
      const float qk0 =  qr * (float)k0;
#pragma unroll
      for (int g = 0; g < 2; ++g) {
        const int d0 = 2 * jl[g] - r0;
        const float P0 = fmaf(cr, (float)(d0 * d0), jbase[g] + bk);
        const float P1 = -4.f * fmaf(cr, (float)d0, qk0);
        float wv[8];
#pragma unroll
        for (int e = 0; e < 8; ++e) {
          const float ef = (float)e;
          const float ph = fmaf(ef, fmaf(ef, P2r, P1), P0);
          wv[e] = __builtin_amdgcn_cosf(__builtin_amdgcn_fractf(ph));
        }
        const half8 bh = pack8(wv);
#pragma unroll
        for (int fm = 0; fm < 4; ++fm)
          acc[fm][g] = __builtin_amdgcn_mfma_f32_16x16x32_f16(af[fm], bh, acc[fm][g], 0, 0, 0);
      }
    }
    {
      char* base = (char*)&U[cb ^ 1][srow][0];
#pragma unroll
      for (int k = 0; k < 4; ++k) {
        const int s = t15 + 16 * k;
        *(u32x4*)(base + ((gpos(s) << 4) ^ swz)) = po[k];
      }
    }
  }

  // ODD pass (r = 2i+1, A from xiT); odd chunk 0 already in U[0]
  for (int ch = 0; ch < 8; ++ch) {
    __syncthreads();
    const int cb = ch & 1;
    if (ch < 7) {
#pragma unroll
      for (int k = 0; k < 4; ++k)
        po[k] = *(const u32x4*)(orow + (ch + 1) * CHW + (t15 + 16 * k) * 8);
    }
#pragma unroll
    for (int st = 0; st < 2; ++st) {
      const int sg = kq * 8 + st * 4 + lhi;
      const int go = gpos(sg) << 4;
      half8 af[4];
#pragma unroll
      for (int fm = 0; fm < 4; ++fm) {
        const int row = fm * 16 + l15;
        af[fm] = *(const half8*)((const char*)&U[cb][row][0] + (go ^ ((row & 7) << 4)));
      }
      const int i0 = ch * CHW + kq * 64 + st * 32 + lhi * 8;
      const int r0 = 2 * i0 + 1;
      const int k0 = r0 - (NN - 1);
      const float bk  = -qr * (float)(k0 * k0);
      const float qk0 =  qr * (float)k0;
#pragma unroll
      for (int g = 0; g < 2; ++g) {
        const int d0 = 2 * jl[g] - r0;
        const float P0 = fmaf(cr, (float)(d0 * d0), jbase[g] + bk);
        const float P1 = -4.f * fmaf(cr, (float)d0, qk0);
        float wv[8];
#pragma unroll
        for (int e = 0; e < 8; ++e) {
          const float ef = (float)e;
          const float ph = fmaf(ef, fmaf(ef, P2r, P1), P0);
          float t = __builtin_amdgcn_cosf(__builtin_amdgcn_fractf(ph));
          if (i0 + e > NN - 2) t = 0.f;   // r=8191 pad does not exist
          wv[e] = t;
        }
        const half8 bh = pack8(wv);
#pragma unroll
        for (int fm = 0; fm < 4; ++fm)
          acc[fm][g] = __builtin_amdgcn_mfma_f32_16x16x32_f16(af[fm], bh, acc[fm][g], 0, 0, 0);
      }
    }
    if (ch < 7) {
      char* base = (char*)&U[cb ^ 1][srow][0];
#pragma unroll
      for (int k = 0; k < 4; ++k) {
        const int s = t15 + 16 * k;
        *(u32x4*)(base + ((gpos(s) << 4) ^ swz)) = po[k];
      }
    }
  }

  // 8 kq-partials -> 4 red planes in 2 rounds + scaled store
  __syncthreads();
  if (kq < 4) {
#pragma unroll
    for (int fm = 0; fm < 4; ++fm)
#pragma unroll
      for (int g = 0; g < 2; ++g)
#pragma unroll
        for (int rr = 0; rr < 4; ++rr)
          redf[((kq * 64) + fm * 16 + lhi * 4 + rr) * 68 + (fh * 2 + g) * 16 + l15] =
              acc[fm][g][rr];
  }
  __syncthreads();
  if (kq >= 4) {
#pragma unroll
    for (int fm = 0; fm < 4; ++fm)
#pragma unroll
      for (int g = 0; g < 2; ++g)
#pragma unroll
        for (int rr = 0; rr < 4; ++rr)
          redf[(((kq - 4) * 64) + fm * 16 + lhi * 4 + rr) * 68 + (fh * 2 + g) * 16 + l15] +=
              acc[fm][g][rr];
  }
  __syncthreads();

  const int c0 = t15 * 4;
  f32x4 v;
#pragma unroll
  for (int e = 0; e < 4; ++e)
    v[e] = L.scale * (redf[(srow) * 68 + c0 + e] + redf[(64 + srow) * 68 + c0 + e] +
                      redf[(128 + srow) * 68 + c0 + e] + redf[(192 + srow) * 68 + c0 + e]);
  *(f32x4*)(out + (size_t)(b0 + srow) * NN + j0 + c0) = v;
}

// ======================= R13 proven fallback (small ws) =======================

__global__ __launch_bounds__(256) void frft_interp(const float* __restrict__ x,
                                                   __half* __restrict__ xi,
                                                   int b_lo, int cnt,
                                                   uint xi_cap, uint x_cap) {
  __shared__ __align__(16) float wt1[32][64];
  __shared__ __align__(16) float xt[32][64];
  const int tid = threadIdx.x;
  const int s0 = blockIdx.x * 64, cb0 = blockIdx.y * 64;
  const int tx = tid & 15, ty = tid >> 4;
  const int ss0 = ty * 4, bb0 = tx * 4;

  float acc[4][4] = {};
  for (int i0 = 0; i0 < NN; i0 += 32) {
#pragma unroll
    for (int e = 0; e < 8; ++e) {
      int idx = tid + e * 256, qq = idx >> 6, ss = idx & 63;
      int t = s0 + ss - (i0 + qq);
      float sgn = (t & 1) ? -0.63661977236758134f : 0.63661977236758134f;
      wt1[qq][ss] = __fdividef(sgn, (float)(2 * t + 1));
    }
#pragma unroll
    for (int e = 0; e < 8; ++e) {
      int idx = tid + e * 256, qq = idx >> 6, bb = idx & 63;
      xt[qq][bb] = xload(x, (uint)(b_lo + cb0 + bb) * NN + (i0 + qq), x_cap);
    }
    __syncthreads();
#pragma unroll
    for (int qq = 0; qq < 32; ++qq) {
      float4 wv = *(const float4*)&wt1[qq][ss0];
      float4 uv = *(const float4*)&xt[qq][bb0];
      float w[4] = {wv.x, wv.y, wv.z, wv.w};
      float u[4] = {uv.x, uv.y, uv.z, uv.w};
#pragma unroll
      for (int aa = 0; aa < 4; ++aa)
#pragma unroll
        for (int cc = 0; cc < 4; ++cc) acc[aa][cc] = fmaf(w[aa], u[cc], acc[aa][cc]);
    }
    __syncthreads();
  }
#pragma unroll
  for (int aa = 0; aa < 4; ++aa) {
    int s = s0 + ss0 + aa;
    if (s < NN - 1) {
#pragma unroll
      for (int cc = 0; cc < 4; ++cc) {
        int cb = cb0 + bb0 + cc;
        if (cb < cnt) {
          uint o = (uint)s * (uint)cnt + (uint)cb;
          if (o < xi_cap) xi[o] = __float2half(acc[aa][cc]);
        }
      }
    }
  }
}

#define TJ 32
#define TB 64
#define TK 32
__global__ __launch_bounds__(256) void frft_gemm(const float* __restrict__ x,
                                                 const __half* __restrict__ xi,
                                                 const float* __restrict__ order,
                                                 float* __restrict__ out,
                                                 int b_lo, int cnt,
                                                 uint xi_cap, uint x_cap,
                                                 uint out_capf) {
  __shared__ __align__(16) float wt[TK][TJ];
  __shared__ __align__(16) float ut[TK][TB];
  const int tid = threadIdx.x;
  const int j0 = blockIdx.x * TJ, cb0 = blockIdx.y * TB;
  const int tx = tid & 15, ty = tid >> 4;
  const int jj0 = ty * 2, bb0 = tx * 4;

  LitConsts L = get_lit(order);
  float acc[2][4] = {};

  for (int r0 = 0; r0 < KK; r0 += TK) {
#pragma unroll
    for (int e = 0; e < 4; ++e) {
      int idx = tid + e * 256, qq = idx >> 5, jj = idx & 31;
      int r = r0 + qq;
      float wv = 0.f;
      if (r < KK) {
        int j = j0 + jj;
        int n = 2 * j - (NN - 1);
        int d = 2 * j - r;
        int k = r - (NN - 1);
        float base = fmaf(-L.q, (float)(n * n), L.pe);
        float ph = fmaf(L.c, (float)(d * d), fmaf(-L.q, (float)(k * k), base));
        wv = __cosf(ph);
      }
      wt[qq][jj] = wv;
    }
#pragma unroll
    for (int e = 0; e < 8; ++e) {
      int idx = tid + e * 256, qq = idx >> 6, bb = idx & 63;
      int r = r0 + qq, cb = cb0 + bb;
      float v = 0.f;
      if (r < KK && cb < cnt) {
        if (r & 1) {
          uint o = (uint)(r >> 1) * (uint)cnt + (uint)cb;
          v = (o < xi_cap) ? __half2float(xi[o]) : 0.f;
        } else {
          v = xload(x, (uint)(b_lo + cb) * NN + (uint)(r >> 1), x_cap);
        }
      }
      ut[qq][bb] = v;
    }
    __syncthreads();
#pragma unroll
    for (int qq = 0; qq < TK; ++qq) {
      float2 wv = *(const float2*)&wt[qq][jj0];
      float4 uv = *(const float4*)&ut[qq][bb0];
      float w[2] = {wv.x, wv.y};
      float u[4] = {uv.x, uv.y, uv.z, uv.w};
#pragma unroll
      for (int aa = 0; aa < 2; ++aa)
#pragma unroll
        for (int cc = 0; cc < 4; ++cc)
          acc[aa][cc] = fmaf(w[aa], u[cc], acc[aa][cc]);
    }
    __syncthreads();
  }

#pragma unroll
  for (int aa = 0; aa < 2; ++aa) {
    int j = j0 + jj0 + aa;
#pragma unroll
    for (int cc = 0; cc < 4; ++cc) {
      int cb = cb0 + bb0 + cc;
      if (cb < cnt) {
        uint idx = (uint)(b_lo + cb) * NN + (uint)j;
        if (idx < out_capf) out[idx] = L.scale * acc[aa][cc];
      }
    }
  }
}

__global__ __launch_bounds__(256) void frft_gemm1(const float* __restrict__ x,
                                                  const float* __restrict__ order,
                                                  float* __restrict__ out,
                                                  uint x_cap, uint out_capf) {
  __shared__ float xrow[NN];
  __shared__ float xio[NN - 1];
  __shared__ float red[4][64];
  const int tid = threadIdx.x;
  const int j0 = blockIdx.x * 64;
  LitConsts L = get_lit(order);

#pragma unroll
  for (int e = 0; e < 16; ++e) {
    int i = tid + e * 256;
    xrow[i] = xload(x, (uint)255 * NN + (uint)i, x_cap);
  }
  __syncthreads();
#pragma unroll
  for (int m = 0; m < 16; ++m) {
    int s = tid + m * 256;
    if (s < NN - 1) {
      float a0 = 0.f;
      for (int i = 0; i < NN; ++i) {
        int t = s - i;
        float sgn = (t & 1) ? -0.63661977236758134f : 0.63661977236758134f;
        a0 = fmaf(xrow[i], __fdividef(sgn, (float)(2 * t + 1)), a0);
      }
      xio[s] = a0;
    }
  }
  __syncthreads();

  const int ty = tid >> 6, jj = tid & 63;
  const int j = j0 + jj;
  const int n = 2 * j - (NN - 1);
  const float base = fmaf(-L.q, (float)(n * n), L.pe);
  float acc = 0.f;
  int rend = (ty + 1) * 2048; if (rend > KK) rend = KK;
  for (int r = ty * 2048; r < rend; ++r) {
    int d = 2 * j - r;
    int k = r - (NN - 1);
    float ph = fmaf(L.c, (float)(d * d), fmaf(-L.q, (float)(k * k), base));
    float u = (r & 1) ? xio[r >> 1] : xrow[r >> 1];
    acc = fmaf(__cosf(ph), u, acc);
  }
  red[ty][jj] = acc;
  __syncthreads();
  if (ty == 0) {
    float t = red[0][jj] + red[1][jj] + red[2][jj] + red[3][jj];
    uint idx = (uint)255 * NN + (uint)j;
    if (idx < out_capf) out[idx] = L.scale * t;
  }
}

extern "C" void kernel_launch(void* const* d_in, const int* in_sizes, int n_in,
                              void* d_out, int out_size, void* d_ws, size_t ws_size,
                              hipStream_t stream) {
  const float* x     = (const float*)d_in[0];
  const float* order = (const float*)d_in[1];
  float* outf = (float*)d_out;
  const uint x_cap    = (uint)in_sizes[0];
  const uint out_capf = (uint)out_size;
  const size_t ws_halves = ws_size / 2;

  const size_t XIT_H = (size_t)NN * BB;   // 1,048,576 halves (2 MB)

  // ---- R24 path: xiT (2 MB) + xh (2 MB) in ws; small dirty footprint ----
  if (ws_size >= XIT_H * 2 * 2 &&
      out_capf >= (uint)NN * BB && x_cap >= (uint)NN * BB) {
    _Float16* xiT = (_Float16*)d_ws;
    _Float16* xh  = xiT + XIT_H;
    cvt_x<<<dim3(512), 256, 0, stream>>>(x, xh);
    s1_v6<<<dim3(256), 1024, 0, stream>>>(xh, xiT);
    s2_v6<<<dim3(256), 1024, 0, stream>>>(xh, xiT, order, outf);
    return;
  }

  // ---- R13 proven fallback paths ----
  if (ws_halves >= (size_t)(NN - 1) * BB) {
    uint xi_cap = (uint)((size_t)(NN - 1) * BB);
    frft_interp<<<dim3(64, 4), 256, 0, stream>>>(x, (__half*)d_ws, 0, BB, xi_cap, x_cap);
    frft_gemm<<<dim3(NN / TJ, BB / TB), 256, 0, stream>>>(x, (__half*)d_ws, order, outf,
                                                          0, BB, xi_cap, x_cap, out_capf);
  } else {
    struct Chunk { int lo, cnt; };
    const Chunk ch[6] = { {0,170}, {170,57}, {227,19}, {246,6}, {252,2}, {254,1} };
    for (int i = 0; i < 6; ++i) {
      const Chunk& c = ch[i];
      uint off = (uint)(c.lo + c.cnt) * (uint)NN;
      __half* xp = (__half*)(outf + off);
      size_t need = (size_t)(NN - 1) * (size_t)c.cnt;
      size_t avail = (out_capf > off) ? (size_t)(out_capf - off) * 2 : 0;
      uint xi_cap = (uint)(need < avail ? need : avail);
      frft_interp<<<dim3(64, (unsigned)((c.cnt + 63) / 64)), 256, 0, stream>>>(
          x, xp, c.lo, c.cnt, xi_cap, x_cap);
      frft_gemm<<<dim3(NN / TJ, (unsigned)((c.cnt + TB - 1) / TB)), 256, 0, stream>>>(
          x, xp, order, outf, c.lo, c.cnt, xi_cap, x_cap, out_capf);
    }
    if (ws_halves >= (size_t)(NN - 1)) {
      uint xi_cap = (uint)(NN - 1);
      frft_interp<<<dim3(64, 1), 256, 0, stream>>>(x, (__half*)d_ws, 255, 1, xi_cap, x_cap);
      frft_gemm<<<dim3(NN / TJ, 1), 256, 0, stream>>>(x, (__half*)d_ws, order, outf,
                                                      255, 1, xi_cap, x_cap, out_capf);
    } else {
      frft_gemm1<<<64, 256, 0, stream>>>(x, order, outf, x_cap, out_capf);
    }
  }
}

// Round 12
// 115.212 us; speedup vs baseline: 1.2664x; 1.0020x over previous
//
#include <hip/hip_runtime.h>
#include <hip/hip_fp16.h>
#include <math.h>

// FrFT (Ozaktas, 0.5<a<1.5): x[256,4096] f32, order f32 -> Re(complex64) f32
// out[b*4096+j]. R25: keep R24's s1 Toeplitz win (-12us, proven), revert
// R24's s2 rev-phase (-8us regression: __cosf already lowers to
// v_mul+v_cos; explicit fract+cos broke trans-pipe scheduling).
//   s1_v6: wave frags at s-offsets {fh*16, fh*16+32}; i0 steps 32 between
//   st0->st1 so frag_g1(st1)==frag_g0(st0) bit-identically -> 3 fresh
//   frags/chunk (-25% rcp).
//   s2_v5: R10-proven radian __cosf quadratic-phase weights (40.8us).
// Budget: fill ~41 (harness, unconditional) + cvt 1.5 + s1 ~20 + s2 ~41.
// Weight math proven through R13-R24; odd pad r=8191 weight-zeroed.

#define NN 4096
#define BB 256
#define KK (2*NN - 1)
#define CHW 512

typedef unsigned int uint;
typedef __attribute__((ext_vector_type(4))) float f32x4;
typedef __attribute__((ext_vector_type(4))) uint u32x4;
typedef __attribute__((ext_vector_type(8))) _Float16 half8;
typedef __attribute__((ext_vector_type(4))) _Float16 half4;
typedef __attribute__((ext_vector_type(2))) __fp16 fp16x2;

struct LitConsts { float c, q, scale, pe; };

__device__ __forceinline__ LitConsts get_lit(const float* order) {
  float a = order[0];
  float alpha = a * (float)M_PI * 0.5f;
  float sina = sinf(alpha);
  float tana2 = tanf(alpha * 0.5f);
  LitConsts L;
  L.c = (float)M_PI / (float)NN / sina / 4.0f;
  L.q = ((float)M_PI / (float)NN) * (tana2 * 0.25f);
  L.scale = sqrtf(L.c / (float)M_PI);
  L.pe = -(1.0f - a) * (float)M_PI * 0.25f;
  return L;
}

__device__ __forceinline__ float xload(const float* __restrict__ x, uint idx, uint cap) {
  return (idx < cap) ? x[idx] : 0.f;
}

__device__ __forceinline__ uint pk2(float a, float b) {
  fp16x2 h = __builtin_amdgcn_cvt_pkrtz(a, b);
  return __builtin_bit_cast(uint, h);
}

__device__ __forceinline__ half8 pack8(const float* wv) {
  u32x4 u = { pk2(wv[0], wv[1]), pk2(wv[2], wv[3]),
              pk2(wv[4], wv[5]), pk2(wv[6], wv[7]) };
  return __builtin_bit_cast(half8, u);
}

// granule position permutation (16B granules within a 64-granule row)
__device__ __forceinline__ int gpos(int s) { return s ^ (s >> 3); }

// sinc Toeplitz weight fragment: elements e=0..7 at t = t0 - e (R13-proven math)
__device__ __forceinline__ half8 mkw1(int t0) {
  const float C2PI = 0.63661977236758134f;
  float wv[8];
#pragma unroll
  for (int e = 0; e < 8; ++e) {
    const int t = t0 - e;
    const float sgn = (t & 1) ? -C2PI : C2PI;
    wv[e] = __fdividef(sgn, (float)(2 * t + 1));
  }
  return pack8(wv);
}

// ---- one-time x -> f16 (RTZ, same values R8 staged in LDS) ----
__global__ __launch_bounds__(256) void cvt_x(const float* __restrict__ x,
                                             _Float16* __restrict__ xh) {
  const int g = blockIdx.x * 256 + threadIdx.x;      // granule id (8 f32 each)
  const f32x4* p = (const f32x4*)(x + (size_t)g * 8);
  f32x4 a = p[0], b = p[1];
  u32x4 d = { pk2(a[0], a[1]), pk2(a[2], a[3]), pk2(b[0], b[1]), pk2(b[2], b[3]) };
  *(u32x4*)(xh + (size_t)g * 8) = d;
}

// ---- stage 1: sinc interp GEMM; 256 blocks x 1024 thr; tile 64b x 64s ----
// Wave frags at s-offsets {fh*16, fh*16+32}; frag_g1(st1) == frag_g0(st0).
__global__ __launch_bounds__(1024, 4) void s1_v6(const _Float16* __restrict__ xh,
                                                 _Float16* __restrict__ xiT) {
  __shared__ __align__(16) _Float16 U[2][64][CHW];   // 128 KB
  float* redf = (float*)&U[0][0][0];                 // aliased after k-loop
  const int tid = threadIdx.x;
  const int w = tid >> 6, lane = tid & 63;
  const int l15 = lane & 15, lhi = lane >> 4;
  const int kq = w & 7, fh = w >> 3;
  const int id = blockIdx.x, xcd = id & 7;
  const int b0 = (xcd >> 1) * 64;                    // same-b blocks -> XCD
  const int s0 = ((xcd & 1) | ((id >> 3) << 1)) * 64;
  const int srow = tid >> 4, t15 = tid & 15;
  const int swz = (srow & 7) << 4;

  const _Float16* xrow = xh + (size_t)(b0 + srow) * NN;

  f32x4 acc[4][2] = {};   // [fm][g]; g=0 -> s-off fh*16, g=1 -> fh*16+32
  u32x4 po[4];

  { // prologue: stage chunk 0
#pragma unroll
    for (int k = 0; k < 4; ++k)
      po[k] = *(const u32x4*)(xrow + (t15 + 16 * k) * 8);
    char* base = (char*)&U[0][srow][0];
#pragma unroll
    for (int k = 0; k < 4; ++k) {
      const int s = t15 + 16 * k;
      *(u32x4*)(base + ((gpos(s) << 4) ^ swz)) = po[k];
    }
  }

  for (int ch = 0; ch < 8; ++ch) {
    __syncthreads();
    const int cb = ch & 1;
    if (ch < 7) {
#pragma unroll
      for (int k = 0; k < 4; ++k)
        po[k] = *(const u32x4*)(xrow + (ch + 1) * CHW + (t15 + 16 * k) * 8);
    }
    const int i00 = ch * CHW + kq * 64 + lhi * 8;    // st = 0 k-base
    const int t00 = (s0 + fh * 16 + l15) - i00;      // g0 @ st0
    half8 keep;                                      // frag reused at st1/g1
    // ---- st = 0 ----
    {
      const int sg = kq * 8 + lhi;
      const int go = gpos(sg) << 4;
      half8 af[4];
#pragma unroll
      for (int fm = 0; fm < 4; ++fm) {
        const int row = fm * 16 + l15;
        af[fm] = *(const half8*)((const char*)&U[cb][row][0] + (go ^ ((row & 7) << 4)));
      }
      keep = mkw1(t00);                              // fresh g0
      const half8 bh1 = mkw1(t00 + 32);              // fresh g1
#pragma unroll
      for (int fm = 0; fm < 4; ++fm) {
        acc[fm][0] = __builtin_amdgcn_mfma_f32_16x16x32_f16(af[fm], keep, acc[fm][0], 0, 0, 0);
        acc[fm][1] = __builtin_amdgcn_mfma_f32_16x16x32_f16(af[fm], bh1, acc[fm][1], 0, 0, 0);
      }
    }
    // ---- st = 1 (i0 += 32): g1 reuses st0's g0 frag bit-identically ----
    {
      const int sg = kq * 8 + 4 + lhi;
      const int go = gpos(sg) << 4;
      half8 af[4];
#pragma unroll
      for (int fm = 0; fm < 4; ++fm) {
        const int row = fm * 16 + l15;
        af[fm] = *(const half8*)((const char*)&U[cb][row][0] + (go ^ ((row & 7) << 4)));
      }
      const half8 bh0 = mkw1(t00 - 32);              // fresh g0
#pragma unroll
      for (int fm = 0; fm < 4; ++fm) {
        acc[fm][0] = __builtin_amdgcn_mfma_f32_16x16x32_f16(af[fm], bh0, acc[fm][0], 0, 0, 0);
        acc[fm][1] = __builtin_amdgcn_mfma_f32_16x16x32_f16(af[fm], keep, acc[fm][1], 0, 0, 0);
      }
    }
    if (ch < 7) {
      char* base = (char*)&U[cb ^ 1][srow][0];
#pragma unroll
      for (int k = 0; k < 4; ++k) {
        const int s = t15 + 16 * k;
        *(u32x4*)(base + ((gpos(s) << 4) ^ swz)) = po[k];
      }
    }
  }

  // 8 kq-partials -> 4 red planes (aliased over U) in 2 rounds
  __syncthreads();
  if (kq < 4) {
#pragma unroll
    for (int fm = 0; fm < 4; ++fm)
#pragma unroll
      for (int g = 0; g < 2; ++g)
#pragma unroll
        for (int rr = 0; rr < 4; ++rr)
          redf[((kq * 64) + fm * 16 + lhi * 4 + rr) * 68 + fh * 16 + g * 32 + l15] =
              acc[fm][g][rr];
  }
  __syncthreads();
  if (kq >= 4) {
#pragma unroll
    for (int fm = 0; fm < 4; ++fm)
#pragma unroll
      for (int g = 0; g < 2; ++g)
#pragma unroll
        for (int rr = 0; rr < 4; ++rr)
          redf[(((kq - 4) * 64) + fm * 16 + lhi * 4 + rr) * 68 + fh * 16 + g * 32 + l15] +=
              acc[fm][g][rr];
  }
  __syncthreads();

  const int c0 = t15 * 4;
  half4 h;
#pragma unroll
  for (int e = 0; e < 4; ++e)
    h[e] = (_Float16)(redf[(srow) * 68 + c0 + e] + redf[(64 + srow) * 68 + c0 + e] +
                      redf[(128 + srow) * 68 + c0 + e] + redf[(192 + srow) * 68 + c0 + e]);
  *(half4*)(xiT + (size_t)(b0 + srow) * NN + s0 + c0) = h;
}

// ---- stage 2: fused even+odd chirp GEMM; R10-proven __cosf weights ----
__global__ __launch_bounds__(1024, 4) void s2_v5(const _Float16* __restrict__ xh,
                                                 const _Float16* __restrict__ xiT,
                                                 const float* __restrict__ order,
                                                 float* __restrict__ out) {
  __shared__ __align__(16) _Float16 U[2][64][CHW];
  float* redf = (float*)&U[0][0][0];
  const int tid = threadIdx.x;
  const int w = tid >> 6, lane = tid & 63;
  const int l15 = lane & 15, lhi = lane >> 4;
  const int kq = w & 7, fh = w >> 3;
  const int id = blockIdx.x, xcd = id & 7;
  const int b0 = (xcd >> 1) * 64;
  const int j0 = ((xcd & 1) | ((id >> 3) << 1)) * 64;
  const int srow = tid >> 4, t15 = tid & 15;
  const int swz = (srow & 7) << 4;

  const LitConsts L = get_lit(order);
  const float P2 = 4.f * (L.c - L.q);
  int jl[2]; float jbase[2];
#pragma unroll
  for (int g = 0; g < 2; ++g) {
    jl[g] = j0 + (fh * 2 + g) * 16 + l15;
    const int n = 2 * jl[g] - (NN - 1);
    jbase[g] = fmaf(-L.q, (float)(n * n), L.pe);
  }

  const _Float16* xrow = xh + (size_t)(b0 + srow) * NN;
  const _Float16* orow = xiT + (size_t)(b0 + srow) * NN;

  f32x4 acc[4][2] = {};
  u32x4 po[4];

  { // prologue: stage even chunk 0
#pragma unroll
    for (int k = 0; k < 4; ++k)
      po[k] = *(const u32x4*)(xrow + (t15 + 16 * k) * 8);
    char* base = (char*)&U[0][srow][0];
#pragma unroll
    for (int k = 0; k < 4; ++k) {
      const int s = t15 + 16 * k;
      *(u32x4*)(base + ((gpos(s) << 4) ^ swz)) = po[k];
    }
  }

  // EVEN pass (r = 2i, A from xh); ch=7 prefetches odd chunk 0 from xiT
  for (int ch = 0; ch < 8; ++ch) {
    __syncthreads();
    const int cb = ch & 1;
    {
      const _Float16* src = (ch < 7) ? (xrow + (ch + 1) * CHW) : orow;
#pragma unroll
      for (int k = 0; k < 4; ++k)
        po[k] = *(const u32x4*)(src + (t15 + 16 * k) * 8);
    }
#pragma unroll
    for (int st = 0; st < 2; ++st) {
      const int sg = kq * 8 + st * 4 + lhi;
      const int go = gpos(sg) << 4;
      half8 af[4];
#pragma unroll
      for (int fm = 0; fm < 4; ++fm) {
        const int row = fm * 16 + l15;
        af[fm] = *(const half8*)((const char*)&U[cb][row][0] + (go ^ ((row & 7) << 4)));
      }
      const int i0 = ch * CHW + kq * 64 + st * 32 + lhi * 8;
      const int r0 = 2 * i0;
      const int k0 = r0 - (NN - 1);
      const float bk  = -L.q * (float)(k0 * k0);
      const float qk0 =  L.q * (float)k0;
#pragma unroll
      for (int g = 0; g < 2; ++g) {
        const int d0 = 2 * jl[g] - r0;
        const float P0 = fmaf(L.c, (float)(d0 * d0), jbase[g] + bk);
        const float P1 = -4.f * fmaf(L.c, (float)d0, qk0);
        float wv[8];
#pragma unroll
        for (int e = 0; e < 8; ++e) {
          const float ef = (float)e;
          wv[e] = __cosf(fmaf(ef, fmaf(ef, P2, P1), P0));
        }
        const half8 bh = pack8(wv);
#pragma unroll
        for (int fm = 0; fm < 4; ++fm)
          acc[fm][g] = __builtin_amdgcn_mfma_f32_16x16x32_f16(af[fm], bh, acc[fm][g], 0, 0, 0);
      }
    }
    {
      char* base = (char*)&U[cb ^ 1][srow][0];
#pragma unroll
      for (int k = 0; k < 4; ++k) {
        const int s = t15 + 16 * k;
        *(u32x4*)(base + ((gpos(s) << 4) ^ swz)) = po[k];
      }
    }
  }

  // ODD pass (r = 2i+1, A from xiT); odd chunk 0 already in U[0]
  for (int ch = 0; ch < 8; ++ch) {
    __syncthreads();
    const int cb = ch & 1;
    if (ch < 7) {
#pragma unroll
      for (int k = 0; k < 4; ++k)
        po[k] = *(const u32x4*)(orow + (ch + 1) * CHW + (t15 + 16 * k) * 8);
    }
#pragma unroll
    for (int st = 0; st < 2; ++st) {
      const int sg = kq * 8 + st * 4 + lhi;
      const int go = gpos(sg) << 4;
      half8 af[4];
#pragma unroll
      for (int fm = 0; fm < 4; ++fm) {
        const int row = fm * 16 + l15;
        af[fm] = *(const half8*)((const char*)&U[cb][row][0] + (go ^ ((row & 7) << 4)));
      }
      const int i0 = ch * CHW + kq * 64 + st * 32 + lhi * 8;
      const int r0 = 2 * i0 + 1;
      const int k0 = r0 - (NN - 1);
      const float bk  = -L.q * (float)(k0 * k0);
      const float qk0 =  L.q * (float)k0;
#pragma unroll
      for (int g = 0; g < 2; ++g) {
        const int d0 = 2 * jl[g] - r0;
        const float P0 = fmaf(L.c, (float)(d0 * d0), jbase[g] + bk);
        const float P1 = -4.f * fmaf(L.c, (float)d0, qk0);
        float wv[8];
#pragma unroll
        for (int e = 0; e < 8; ++e) {
          const float ef = (float)e;
          float t = __cosf(fmaf(ef, fmaf(ef, P2, P1), P0));
          if (i0 + e > NN - 2) t = 0.f;   // r=8191 pad does not exist
          wv[e] = t;
        }
        const half8 bh = pack8(wv);
#pragma unroll
        for (int fm = 0; fm < 4; ++fm)
          acc[fm][g] = __builtin_amdgcn_mfma_f32_16x16x32_f16(af[fm], bh, acc[fm][g], 0, 0, 0);
      }
    }
    if (ch < 7) {
      char* base = (char*)&U[cb ^ 1][srow][0];
#pragma unroll
      for (int k = 0; k < 4; ++k) {
        const int s = t15 + 16 * k;
        *(u32x4*)(base + ((gpos(s) << 4) ^ swz)) = po[k];
      }
    }
  }

  // 8 kq-partials -> 4 red planes in 2 rounds + scaled store
  __syncthreads();
  if (kq < 4) {
#pragma unroll
    for (int fm = 0; fm < 4; ++fm)
#pragma unroll
      for (int g = 0; g < 2; ++g)
#pragma unroll
        for (int rr = 0; rr < 4; ++rr)
          redf[((kq * 64) + fm * 16 + lhi * 4 + rr) * 68 + (fh * 2 + g) * 16 + l15] =
              acc[fm][g][rr];
  }
  __syncthreads();
  if (kq >= 4) {
#pragma unroll
    for (int fm = 0; fm < 4; ++fm)
#pragma unroll
      for (int g = 0; g < 2; ++g)
#pragma unroll
        for (int rr = 0; rr < 4; ++rr)
          redf[(((kq - 4) * 64) + fm * 16 + lhi * 4 + rr) * 68 + (fh * 2 + g) * 16 + l15] +=
              acc[fm][g][rr];
  }
  __syncthreads();

  const int c0 = t15 * 4;
  f32x4 v;
#pragma unroll
  for (int e = 0; e < 4; ++e)
    v[e] = L.scale * (redf[(srow) * 68 + c0 + e] + redf[(64 + srow) * 68 + c0 + e] +
                      redf[(128 + srow) * 68 + c0 + e] + redf[(192 + srow) * 68 + c0 + e]);
  *(f32x4*)(out + (size_t)(b0 + srow) * NN + j0 + c0) = v;
}

// ======================= R13 proven fallback (small ws) =======================

__global__ __launch_bounds__(256) void frft_interp(const float* __restrict__ x,
                                                   __half* __restrict__ xi,
                                                   int b_lo, int cnt,
                                                   uint xi_cap, uint x_cap) {
  __shared__ __align__(16) float wt1[32][64];
  __shared__ __align__(16) float xt[32][64];
  const int tid = threadIdx.x;
  const int s0 = blockIdx.x * 64, cb0 = blockIdx.y * 64;
  const int tx = tid & 15, ty = tid >> 4;
  const int ss0 = ty * 4, bb0 = tx * 4;

  float acc[4][4] = {};
  for (int i0 = 0; i0 < NN; i0 += 32) {
#pragma unroll
    for (int e = 0; e < 8; ++e) {
      int idx = tid + e * 256, qq = idx >> 6, ss = idx & 63;
      int t = s0 + ss - (i0 + qq);
      float sgn = (t & 1) ? -0.63661977236758134f : 0.63661977236758134f;
      wt1[qq][ss] = __fdividef(sgn, (float)(2 * t + 1));
    }
#pragma unroll
    for (int e = 0; e < 8; ++e) {
      int idx = tid + e * 256, qq = idx >> 6, bb = idx & 63;
      xt[qq][bb] = xload(x, (uint)(b_lo + cb0 + bb) * NN + (i0 + qq), x_cap);
    }
    __syncthreads();
#pragma unroll
    for (int qq = 0; qq < 32; ++qq) {
      float4 wv = *(const float4*)&wt1[qq][ss0];
      float4 uv = *(const float4*)&xt[qq][bb0];
      float w[4] = {wv.x, wv.y, wv.z, wv.w};
      float u[4] = {uv.x, uv.y, uv.z, uv.w};
#pragma unroll
      for (int aa = 0; aa < 4; ++aa)
#pragma unroll
        for (int cc = 0; cc < 4; ++cc) acc[aa][cc] = fmaf(w[aa], u[cc], acc[aa][cc]);
    }
    __syncthreads();
  }
#pragma unroll
  for (int aa = 0; aa < 4; ++aa) {
    int s = s0 + ss0 + aa;
    if (s < NN - 1) {
#pragma unroll
      for (int cc = 0; cc < 4; ++cc) {
        int cb = cb0 + bb0 + cc;
        if (cb < cnt) {
          uint o = (uint)s * (uint)cnt + (uint)cb;
          if (o < xi_cap) xi[o] = __float2half(acc[aa][cc]);
        }
      }
    }
  }
}

#define TJ 32
#define TB 64
#define TK 32
__global__ __launch_bounds__(256) void frft_gemm(const float* __restrict__ x,
                                                 const __half* __restrict__ xi,
                                                 const float* __restrict__ order,
                                                 float* __restrict__ out,
                                                 int b_lo, int cnt,
                                                 uint xi_cap, uint x_cap,
                                                 uint out_capf) {
  __shared__ __align__(16) float wt[TK][TJ];
  __shared__ __align__(16) float ut[TK][TB];
  const int tid = threadIdx.x;
  const int j0 = blockIdx.x * TJ, cb0 = blockIdx.y * TB;
  const int tx = tid & 15, ty = tid >> 4;
  const int jj0 = ty * 2, bb0 = tx * 4;

  LitConsts L = get_lit(order);
  float acc[2][4] = {};

  for (int r0 = 0; r0 < KK; r0 += TK) {
#pragma unroll
    for (int e = 0; e < 4; ++e) {
      int idx = tid + e * 256, qq = idx >> 5, jj = idx & 31;
      int r = r0 + qq;
      float wv = 0.f;
      if (r < KK) {
        int j = j0 + jj;
        int n = 2 * j - (NN - 1);
        int d = 2 * j - r;
        int k = r - (NN - 1);
        float base = fmaf(-L.q, (float)(n * n), L.pe);
        float ph = fmaf(L.c, (float)(d * d), fmaf(-L.q, (float)(k * k), base));
        wv = __cosf(ph);
      }
      wt[qq][jj] = wv;
    }
#pragma unroll
    for (int e = 0; e < 8; ++e) {
      int idx = tid + e * 256, qq = idx >> 6, bb = idx & 63;
      int r = r0 + qq, cb = cb0 + bb;
      float v = 0.f;
      if (r < KK && cb < cnt) {
        if (r & 1) {
          uint o = (uint)(r >> 1) * (uint)cnt + (uint)cb;
          v = (o < xi_cap) ? __half2float(xi[o]) : 0.f;
        } else {
          v = xload(x, (uint)(b_lo + cb) * NN + (uint)(r >> 1), x_cap);
        }
      }
      ut[qq][bb] = v;
    }
    __syncthreads();
#pragma unroll
    for (int qq = 0; qq < TK; ++qq) {
      float2 wv = *(const float2*)&wt[qq][jj0];
      float4 uv = *(const float4*)&ut[qq][bb0];
      float w[2] = {wv.x, wv.y};
      float u[4] = {uv.x, uv.y, uv.z, uv.w};
#pragma unroll
      for (int aa = 0; aa < 2; ++aa)
#pragma unroll
        for (int cc = 0; cc < 4; ++cc)
          acc[aa][cc] = fmaf(w[aa], u[cc], acc[aa][cc]);
    }
    __syncthreads();
  }

#pragma unroll
  for (int aa = 0; aa < 2; ++aa) {
    int j = j0 + jj0 + aa;
#pragma unroll
    for (int cc = 0; cc < 4; ++cc) {
      int cb = cb0 + bb0 + cc;
      if (cb < cnt) {
        uint idx = (uint)(b_lo + cb) * NN + (uint)j;
        if (idx < out_capf) out[idx] = L.scale * acc[aa][cc];
      }
    }
  }
}

__global__ __launch_bounds__(256) void frft_gemm1(const float* __restrict__ x,
                                                  const float* __restrict__ order,
                                                  float* __restrict__ out,
                                                  uint x_cap, uint out_capf) {
  __shared__ float xrow[NN];
  __shared__ float xio[NN - 1];
  __shared__ float red[4][64];
  const int tid = threadIdx.x;
  const int j0 = blockIdx.x * 64;
  LitConsts L = get_lit(order);

#pragma unroll
  for (int e = 0; e < 16; ++e) {
    int i = tid + e * 256;
    xrow[i] = xload(x, (uint)255 * NN + (uint)i, x_cap);
  }
  __syncthreads();
#pragma unroll
  for (int m = 0; m < 16; ++m) {
    int s = tid + m * 256;
    if (s < NN - 1) {
      float a0 = 0.f;
      for (int i = 0; i < NN; ++i) {
        int t = s - i;
        float sgn = (t & 1) ? -0.63661977236758134f : 0.63661977236758134f;
        a0 = fmaf(xrow[i], __fdividef(sgn, (float)(2 * t + 1)), a0);
      }
      xio[s] = a0;
    }
  }
  __syncthreads();

  const int ty = tid >> 6, jj = tid & 63;
  const int j = j0 + jj;
  const int n = 2 * j - (NN - 1);
  const float base = fmaf(-L.q, (float)(n * n), L.pe);
  float acc = 0.f;
  int rend = (ty + 1) * 2048; if (rend > KK) rend = KK;
  for (int r = ty * 2048; r < rend; ++r) {
    int d = 2 * j - r;
    int k = r - (NN - 1);
    float ph = fmaf(L.c, (float)(d * d), fmaf(-L.q, (float)(k * k), base));
    float u = (r & 1) ? xio[r >> 1] : xrow[r >> 1];
    acc = fmaf(__cosf(ph), u, acc);
  }
  red[ty][jj] = acc;
  __syncthreads();
  if (ty == 0) {
    float t = red[0][jj] + red[1][jj] + red[2][jj] + red[3][jj];
    uint idx = (uint)255 * NN + (uint)j;
    if (idx < out_capf) out[idx] = L.scale * t;
  }
}

extern "C" void kernel_launch(void* const* d_in, const int* in_sizes, int n_in,
                              void* d_out, int out_size, void* d_ws, size_t ws_size,
                              hipStream_t stream) {
  const float* x     = (const float*)d_in[0];
  const float* order = (const float*)d_in[1];
  float* outf = (float*)d_out;
  const uint x_cap    = (uint)in_sizes[0];
  const uint out_capf = (uint)out_size;
  const size_t ws_halves = ws_size / 2;

  const size_t XIT_H = (size_t)NN * BB;   // 1,048,576 halves (2 MB)

  // ---- R25 path: xiT (2 MB) + xh (2 MB) in ws; small dirty footprint ----
  if (ws_size >= XIT_H * 2 * 2 &&
      out_capf >= (uint)NN * BB && x_cap >= (uint)NN * BB) {
    _Float16* xiT = (_Float16*)d_ws;
    _Float16* xh  = xiT + XIT_H;
    cvt_x<<<dim3(512), 256, 0, stream>>>(x, xh);
    s1_v6<<<dim3(256), 1024, 0, stream>>>(xh, xiT);
    s2_v5<<<dim3(256), 1024, 0, stream>>>(xh, xiT, order, outf);
    return;
  }

  // ---- R13 proven fallback paths ----
  if (ws_halves >= (size_t)(NN - 1) * BB) {
    uint xi_cap = (uint)((size_t)(NN - 1) * BB);
    frft_interp<<<dim3(64, 4), 256, 0, stream>>>(x, (__half*)d_ws, 0, BB, xi_cap, x_cap);
    frft_gemm<<<dim3(NN / TJ, BB / TB), 256, 0, stream>>>(x, (__half*)d_ws, order, outf,
                                                          0, BB, xi_cap, x_cap, out_capf);
  } else {
    struct Chunk { int lo, cnt; };
    const Chunk ch[6] = { {0,170}, {170,57}, {227,19}, {246,6}, {252,2}, {254,1} };
    for (int i = 0; i < 6; ++i) {
      const Chunk& c = ch[i];
      uint off = (uint)(c.lo + c.cnt) * (uint)NN;
      __half* xp = (__half*)(outf + off);
      size_t need = (size_t)(NN - 1) * (size_t)c.cnt;
      size_t avail = (out_capf > off) ? (size_t)(out_capf - off) * 2 : 0;
      uint xi_cap = (uint)(need < avail ? need : avail);
      frft_interp<<<dim3(64, (unsigned)((c.cnt + 63) / 64)), 256, 0, stream>>>(
          x, xp, c.lo, c.cnt, xi_cap, x_cap);
      frft_gemm<<<dim3(NN / TJ, (unsigned)((c.cnt + TB - 1) / TB)), 256, 0, stream>>>(
          x, xp, order, outf, c.lo, c.cnt, xi_cap, x_cap, out_capf);
    }
    if (ws_halves >= (size_t)(NN - 1)) {
      uint xi_cap = (uint)(NN - 1);
      frft_interp<<<dim3(64, 1), 256, 0, stream>>>(x, (__half*)d_ws, 255, 1, xi_cap, x_cap);
      frft_gemm<<<dim3(NN / TJ, 1), 256, 0, stream>>>(x, (__half*)d_ws, order, outf,
                                                      255, 1, xi_cap, x_cap, out_capf);
    } else {
      frft_gemm1<<<64, 256, 0, stream>>>(x, order, outf, x_cap, out_capf);
    }
  }
}